// Round 1
// baseline (551.959 us; speedup 1.0000x reference)
//
#include <hip/hip_runtime.h>
#include <cstdint>

#define U_NUM 50000
#define F_NUM 20000
#define N_NUM 70000
#define D_EMB 128
#define THRESH 0.3f

// ---------------- GEMM: C[M x 128] = op(A[M x K] @ B[K x 128]) ----------------
// block 256 threads, tile 128(M) x 128(N), KC=32, 8x8 register micro-tile.
template<bool BIAS_RELU, bool NORMS>
__global__ __launch_bounds__(256)
void gemm128(const float* __restrict__ A, const float* __restrict__ B,
             const float* __restrict__ bias, float* __restrict__ C,
             float* __restrict__ norms, int M, int K)
{
    __shared__ float As[32][132];   // k-major, padded
    __shared__ float Bs[32][132];
    const int tid = threadIdx.x;
    const int rg = tid >> 4, cg = tid & 15;
    const int r0 = rg * 8, c0 = cg * 8;
    const int rowBase = blockIdx.x * 128;

    float acc[8][8];
#pragma unroll
    for (int i = 0; i < 8; i++)
#pragma unroll
        for (int j = 0; j < 8; j++) acc[i][j] = 0.f;

    for (int kc = 0; kc < K; kc += 32) {
        // stage A chunk: 128 rows x 32 k (transposed into k-major)
#pragma unroll
        for (int i = 0; i < 16; i++) {
            int flat = i * 256 + tid;
            int r = flat >> 5, k = flat & 31;
            int gr = rowBase + r;
            float v = (gr < M) ? A[(size_t)gr * K + kc + k] : 0.f;
            As[k][r] = v;
        }
        // stage B chunk: 32 k x 128 n
#pragma unroll
        for (int i = 0; i < 16; i++) {
            int flat = i * 256 + tid;
            int k = flat >> 7, n = flat & 127;
            Bs[k][n] = B[(size_t)(kc + k) * 128 + n];
        }
        __syncthreads();
#pragma unroll
        for (int k = 0; k < 32; k++) {
            float4 a0 = *(const float4*)&As[k][r0];
            float4 a1 = *(const float4*)&As[k][r0 + 4];
            float4 b0 = *(const float4*)&Bs[k][c0];
            float4 b1 = *(const float4*)&Bs[k][c0 + 4];
            float av[8] = {a0.x, a0.y, a0.z, a0.w, a1.x, a1.y, a1.z, a1.w};
            float bv[8] = {b0.x, b0.y, b0.z, b0.w, b1.x, b1.y, b1.z, b1.w};
#pragma unroll
            for (int i = 0; i < 8; i++)
#pragma unroll
                for (int j = 0; j < 8; j++)
                    acc[i][j] += av[i] * bv[j];
        }
        __syncthreads();
    }

    float bb[8];
    if (BIAS_RELU) {
#pragma unroll
        for (int j = 0; j < 8; j++) bb[j] = bias[c0 + j];
    }

#pragma unroll
    for (int i = 0; i < 8; i++) {
        int gr = rowBase + r0 + i;
        bool valid = (gr < M);
        float v[8];
#pragma unroll
        for (int j = 0; j < 8; j++) {
            float x = acc[i][j];
            if (BIAS_RELU) { x += bb[j]; x = fmaxf(x, 0.f); }
            v[j] = x;
        }
        if (NORMS) {
            float p = 0.f;
#pragma unroll
            for (int j = 0; j < 8; j++) p += v[j] * v[j];
            p += __shfl_xor(p, 1);
            p += __shfl_xor(p, 2);
            if (valid && ((cg & 3) == 0))
                norms[(size_t)gr * 4 + (cg >> 2)] = sqrtf(p);
        }
        if (valid) {
            *(float4*)(C + (size_t)gr * 128 + c0)     = make_float4(v[0], v[1], v[2], v[3]);
            *(float4*)(C + (size_t)gr * 128 + c0 + 4) = make_float4(v[4], v[5], v[6], v[7]);
        }
    }
}

// ---------------- per-(undirected)-edge multi-head cosine mask ----------------
// 8 lanes per edge; Q/K rows gathered as float4s; per-head partials shuffled.
__global__ __launch_bounds__(256)
void edge_kernel(const int* __restrict__ ei, int Edir,
                 const float* __restrict__ Q, const float* __restrict__ Kf,
                 const float* __restrict__ qn, const float* __restrict__ kn,
                 const float* __restrict__ cwts,
                 float* __restrict__ maskf, int* __restrict__ cnt, int Eund)
{
    int gid = blockIdx.x * 256 + threadIdx.x;
    int e = gid >> 3;
    if (e >= Eund) return;
    int sub = gid & 7;
    int row = ei[e];
    int col = ei[Edir + e];
    row = min(max(row, 0), N_NUM - 1);
    col = min(max(col, 0), N_NUM - 1);
    int u  = (row < U_NUM) ? row : col;
    int fg = (row < U_NUM) ? col : row;
    u = min(max(u, 0), U_NUM - 1);
    int f = min(max(fg - U_NUM, 0), F_NUM - 1);

    const float4* qp = (const float4*)(Q  + (size_t)u * D_EMB + sub * 16);
    const float4* kp = (const float4*)(Kf + (size_t)f * D_EMB + sub * 16);
    float dot = 0.f;
#pragma unroll
    for (int i = 0; i < 4; i++) {
        float4 a = qp[i]; float4 b = kp[i];
        dot += a.x * b.x + a.y * b.y + a.z * b.z + a.w * b.w;
    }
    dot += __shfl_xor(dot, 1);           // 16+16 -> 32-elem head dot
    int h = sub >> 1;
    float denom = qn[u * 4 + h] * kn[f * 4 + h] + 1e-8f;
    float sim = dot / denom;
    float s = sim + __shfl_xor(sim, 2);  // pairs of heads
    s += __shfl_xor(s, 4);               // all 4 heads
    float mean = s * 0.25f;
    float mf = (mean > THRESH) ? 1.f : 0.f;

    float cw0 = cwts[0], cw1 = cwts[1];
    float mx = fmaxf(cw0, cw1);
    float e0 = expf(cw0 - mx), e1 = expf(cw1 - mx);
    float inv = 1.f / (e0 + e1);
    float fused = e0 * inv + (e1 * inv) * mf;
    float em = (fused > 0.5f) ? 1.f : 0.f;

    if (sub == 0) {
        maskf[e] = em;
        if (em != 0.f) {
            atomicAdd(&cnt[row], 1);
            atomicAdd(&cnt[col], 1);
        }
    }
}

// ---------------- exclusive scan over cnt[N] (3 kernels) ----------------
__global__ void scan_part(const int* __restrict__ cnt, int* __restrict__ part, int n)
{
    __shared__ int sd[256];
    int b = blockIdx.x, t = threadIdx.x;
    int base = b * 1024;
    int s = 0;
#pragma unroll
    for (int j = 0; j < 4; j++) {
        int idx = base + t + j * 256;
        if (idx < n) s += cnt[idx];
    }
    sd[t] = s; __syncthreads();
    for (int d = 128; d > 0; d >>= 1) {
        if (t < d) sd[t] += sd[t + d];
        __syncthreads();
    }
    if (t == 0) part[b] = sd[0];
}

__global__ void scan_small(int* part, int nb)  // exclusive in place, nb<=256
{
    __shared__ int sd[256];
    int t = threadIdx.x;
    sd[t] = (t < nb) ? part[t] : 0;
    __syncthreads();
    for (int d = 1; d < 256; d <<= 1) {
        int x = (t >= d) ? sd[t - d] : 0;
        __syncthreads();
        sd[t] += x;
        __syncthreads();
    }
    if (t < nb) part[t] = (t > 0) ? sd[t - 1] : 0;
}

__global__ void scan_final(const int* __restrict__ cnt, const int* __restrict__ part,
                           int* __restrict__ offs, int n)
{
    __shared__ int sd[256];
    int b = blockIdx.x, t = threadIdx.x;
    int base = b * 1024 + t * 4;
    int v[4]; int s = 0;
#pragma unroll
    for (int j = 0; j < 4; j++) {
        int idx = base + j;
        v[j] = (idx < n) ? cnt[idx] : 0;
        s += v[j];
    }
    sd[t] = s; __syncthreads();
    for (int d = 1; d < 256; d <<= 1) {
        int x = (t >= d) ? sd[t - d] : 0;
        __syncthreads();
        sd[t] += x;
        __syncthreads();
    }
    int prefix = part[b] + ((t > 0) ? sd[t - 1] : 0);
#pragma unroll
    for (int j = 0; j < 4; j++) {
        int idx = base + j;
        if (idx < n) offs[idx] = prefix;
        prefix += v[j];
    }
}

// ---------------- CSR scatter (both directions of each masked edge) ----------------
__global__ void scatter_kernel(const int* __restrict__ ei, int Edir,
                               const float* __restrict__ maskf,
                               const int* __restrict__ cnt, const int* __restrict__ offs,
                               int* __restrict__ cursor,
                               int* __restrict__ cnbr, float* __restrict__ cwA, int Eund)
{
    int e = blockIdx.x * 256 + threadIdx.x;
    if (e >= Eund) return;
    if (maskf[e] == 0.f) return;
    int row = ei[e], col = ei[Edir + e];
    row = min(max(row, 0), N_NUM - 1);
    col = min(max(col, 0), N_NUM - 1);
    float w = 1.0f / sqrtf((float)cnt[row] * (float)cnt[col]);
    int p1 = offs[row] + atomicAdd(&cursor[row], 1);
    cnbr[p1] = col; cwA[p1] = w;
    int p2 = offs[col] + atomicAdd(&cursor[col], 1);
    cnbr[p2] = row; cwA[p2] = w;
}

// ---------------- misc ----------------
__global__ void zero2(int* __restrict__ a, int* __restrict__ b, int n)
{
    int i = blockIdx.x * 256 + threadIdx.x;
    if (i < n) { a[i] = 0; b[i] = 0; }
}

__global__ void initx(const float* __restrict__ ue, const float* __restrict__ ie,
                      float* __restrict__ xcur, float* __restrict__ accb)
{
    int i = blockIdx.x * 256 + threadIdx.x;   // float4 index
    const int total = N_NUM * (D_EMB / 4);
    if (i >= total) return;
    const int u4 = U_NUM * (D_EMB / 4);
    float4 v = (i < u4) ? ((const float4*)ue)[i] : ((const float4*)ie)[i - u4];
    ((float4*)xcur)[i] = v;
    ((float4*)accb)[i] = v;
}

// one wave per node; float2 per lane covers D=128
__global__ __launch_bounds__(256)
void prop(const int* __restrict__ offs, const int* __restrict__ cnt,
          const int* __restrict__ cnbr, const float* __restrict__ cwA,
          const float* __restrict__ xin, float* __restrict__ xout,
          float* __restrict__ accb)
{
    int wid = (blockIdx.x << 2) + (threadIdx.x >> 6);
    if (wid >= N_NUM) return;
    int lane = threadIdx.x & 63;
    int start = offs[wid], num = cnt[wid];
    float ax = 0.f, ay = 0.f;
    int j = 0;
    for (; j + 4 <= num; j += 4) {
        int c0i = cnbr[start + j], c1i = cnbr[start + j + 1];
        int c2i = cnbr[start + j + 2], c3i = cnbr[start + j + 3];
        float w0 = cwA[start + j], w1 = cwA[start + j + 1];
        float w2 = cwA[start + j + 2], w3 = cwA[start + j + 3];
        float2 v0 = *(const float2*)(xin + (size_t)c0i * D_EMB + lane * 2);
        float2 v1 = *(const float2*)(xin + (size_t)c1i * D_EMB + lane * 2);
        float2 v2 = *(const float2*)(xin + (size_t)c2i * D_EMB + lane * 2);
        float2 v3 = *(const float2*)(xin + (size_t)c3i * D_EMB + lane * 2);
        ax += w0 * v0.x; ay += w0 * v0.y;
        ax += w1 * v1.x; ay += w1 * v1.y;
        ax += w2 * v2.x; ay += w2 * v2.y;
        ax += w3 * v3.x; ay += w3 * v3.y;
    }
    for (; j < num; ++j) {
        int c = cnbr[start + j]; float w = cwA[start + j];
        float2 v = *(const float2*)(xin + (size_t)c * D_EMB + lane * 2);
        ax += w * v.x; ay += w * v.y;
    }
    size_t o = (size_t)wid * D_EMB + lane * 2;
    *(float2*)(xout + o) = make_float2(ax, ay);
    float2 a = *(float2*)(accb + o);
    *(float2*)(accb + o) = make_float2(a.x + ax, a.y + ay);
}

__global__ void final_kernel(const float* __restrict__ ue, const float* __restrict__ ie,
                             float* __restrict__ out)
{
    int i = blockIdx.x * 256 + threadIdx.x;   // float4 index
    const int nd4 = N_NUM * (D_EMB / 4);
    const int u4  = U_NUM * (D_EMB / 4);
    const int f4  = F_NUM * (D_EMB / 4);
    if (i < nd4) {
        float4 v = ((float4*)out)[i];
        v.x *= 0.25f; v.y *= 0.25f; v.z *= 0.25f; v.w *= 0.25f;
        ((float4*)out)[i] = v;
    } else if (i < nd4 + u4) {
        ((float4*)out)[i] = ((const float4*)ue)[i - nd4];
    } else if (i < nd4 + u4 + f4) {
        ((float4*)out)[i] = ((const float4*)ie)[i - nd4 - u4];
    }
}

// ---------------- launcher ----------------
extern "C" void kernel_launch(void* const* d_in, const int* in_sizes, int n_in,
                              void* d_out, int out_size, void* d_ws, size_t ws_size,
                              hipStream_t stream)
{
    const float* user_feat  = (const float*)d_in[0];
    const float* food_feat  = (const float*)d_in[1];
    const int*   ei         = (const int*)d_in[2];
    const float* W_user     = (const float*)d_in[3];
    const float* b_user     = (const float*)d_in[4];
    const float* W_food     = (const float*)d_in[5];
    const float* b_food     = (const float*)d_in[6];
    const float* Wq         = (const float*)d_in[7];
    const float* Wk         = (const float*)d_in[8];
    const float* cwts       = (const float*)d_in[9];
    const float* user_embed = (const float*)d_in[10];
    const float* item_embed = (const float*)d_in[11];

    const int Edir = in_sizes[2] / 2;   // 1.2M directed edges
    const int Eund = Edir / 2;          // 600K undirected (structure: [u,f] || [f,u])

    char* ws = (char*)d_ws;
    size_t off = 0;
    auto alloc = [&](size_t nb) { size_t o = off; off += (nb + 255) & ~(size_t)255; return o; };

    float* Q     = (float*)(ws + alloc((size_t)U_NUM * D_EMB * 4));   // Q|Kf contiguous -> reused as xcur
    float* Kf    = (float*)(ws + alloc((size_t)F_NUM * D_EMB * 4));
    float* qn    = (float*)(ws + alloc((size_t)U_NUM * 4 * 4));
    float* kn    = (float*)(ws + alloc((size_t)F_NUM * 4 * 4));
    float* xnext = (float*)(ws + alloc((size_t)N_NUM * D_EMB * 4));   // also hosts E_user|E_food early
    float* maskf = (float*)(ws + alloc((size_t)Eund * 4));
    int*   cnt   = (int*)  (ws + alloc((size_t)N_NUM * 4));
    int*   offs  = (int*)  (ws + alloc((size_t)N_NUM * 4));
    int*   cursor= (int*)  (ws + alloc((size_t)N_NUM * 4));
    int*   cnbr  = (int*)  (ws + alloc((size_t)Edir * 4));
    float* cwA   = (float*)(ws + alloc((size_t)Edir * 4));
    int*   part  = (int*)  (ws + alloc((size_t)256 * 4));
    (void)ws_size; (void)n_in; (void)out_size;

    float* xcur  = Q;                       // alias after edge stage
    float* Euser = xnext;                   // alias before propagation
    float* Efood = xnext + (size_t)U_NUM * D_EMB;
    float* accb  = (float*)d_out;           // accumulator lives in d_out[0 : N*D]

    // 1) zero counters
    zero2<<<(N_NUM + 255) / 256, 256, 0, stream>>>(cnt, cursor, N_NUM);

    // 2) projections (f32 vector GEMMs)
    gemm128<true,  false><<<(U_NUM + 127) / 128, 256, 0, stream>>>(user_feat, W_user, b_user, Euser, nullptr, U_NUM, 256);
    gemm128<true,  false><<<(F_NUM + 127) / 128, 256, 0, stream>>>(food_feat, W_food, b_food, Efood, nullptr, F_NUM, 256);
    gemm128<false, true ><<<(U_NUM + 127) / 128, 256, 0, stream>>>(Euser, Wq, nullptr, Q,  qn, U_NUM, 128);
    gemm128<false, true ><<<(F_NUM + 127) / 128, 256, 0, stream>>>(Efood, Wk, nullptr, Kf, kn, F_NUM, 128);

    // 3) per-edge mask + degree counts
    edge_kernel<<<(Eund * 8 + 255) / 256, 256, 0, stream>>>(ei, Edir, Q, Kf, qn, kn, cwts, maskf, cnt, Eund);

    // 4) exclusive scan of cnt -> offs
    int nb = (N_NUM + 1023) / 1024;
    scan_part <<<nb, 256, 0, stream>>>(cnt, part, N_NUM);
    scan_small<<<1, 256, 0, stream>>>(part, nb);
    scan_final<<<nb, 256, 0, stream>>>(cnt, part, offs, N_NUM);

    // 5) CSR scatter
    scatter_kernel<<<(Eund + 255) / 256, 256, 0, stream>>>(ei, Edir, maskf, cnt, offs, cursor, cnbr, cwA, Eund);

    // 6) x0 into xcur (over dead Q|K) and acc (d_out)
    initx<<<(N_NUM * (D_EMB / 4) + 255) / 256, 256, 0, stream>>>(user_embed, item_embed, xcur, accb);

    // 7) three LightGCN layers (ping-pong)
    int pb = (N_NUM + 3) / 4;
    prop<<<pb, 256, 0, stream>>>(offs, cnt, cnbr, cwA, xcur,  xnext, accb);
    prop<<<pb, 256, 0, stream>>>(offs, cnt, cnbr, cwA, xnext, xcur,  accb);
    prop<<<pb, 256, 0, stream>>>(offs, cnt, cnbr, cwA, xcur,  xnext, accb);

    // 8) scale 1/4 + copy embeds
    final_kernel<<<(2 * N_NUM * (D_EMB / 4) + 255) / 256, 256, 0, stream>>>(user_embed, item_embed, (float*)d_out);
}

// Round 2
// 315.718 us; speedup vs baseline: 1.7483x; 1.7483x over previous
//
#include <hip/hip_runtime.h>
#include <cstdint>

#define U_NUM 50000
#define F_NUM 20000
#define N_NUM 70000
#define D_EMB 128
#define THRESH 0.3f

// ============ fused projection: Q = relu(A@W1 + b1) @ W2, + per-head norms ============
// One dispatch covers users (blocks [0,nbU)) and foods (blocks [nbU,nbU+nbF)).
// Tile: 64 rows x 128 cols, 256 threads, 4x8 register micro-tile, K1=256, K2=128.
// LDS (floats): Es[128][68] at [0,8704) (stage2, overlaps stage1 region timeline-separated),
//               stage1: As[32][68] at [0,2176), W1s[32][132] at [2176,6400),
//               stage2: W2s[32][132] at [8704,12928).  Total 51712 B -> 3 blocks/CU.
__global__ __launch_bounds__(256)
void fused_proj(const float* __restrict__ uf, const float* __restrict__ ff,
                const float* __restrict__ Wu, const float* __restrict__ bu,
                const float* __restrict__ Wf, const float* __restrict__ bfo,
                const float* __restrict__ Wq, const float* __restrict__ Wk,
                float* __restrict__ Qo, float* __restrict__ Ko,
                float* __restrict__ qn, float* __restrict__ kn, int nbU)
{
    __shared__ float lds[12928];
    float* Es  = lds;          // [128][68]
    float* As  = lds;          // [32][68]  (stage1 only)
    float* W1s = lds + 2176;   // [32][132] (stage1 only)
    float* W2s = lds + 8704;   // [32][132] (stage2)

    const bool isU = ((int)blockIdx.x < nbU);
    const float* A   = isU ? uf : ff;
    const float* W1  = isU ? Wu : Wf;
    const float* b1  = isU ? bu : bfo;
    const float* W2  = isU ? Wq : Wk;
    float* out       = isU ? Qo : Ko;
    float* norms     = isU ? qn : kn;
    const int M      = isU ? U_NUM : F_NUM;
    const int rowBase = (isU ? (int)blockIdx.x : ((int)blockIdx.x - nbU)) * 64;

    const int tid = threadIdx.x;
    const int rg = tid >> 4, cg = tid & 15;
    const int r0 = rg * 4, c0 = cg * 8;

    // ---- stage 1: E[64][128] = relu(A[64x256] @ W1[256x128] + b1) ----
    float acc[4][8];
#pragma unroll
    for (int i = 0; i < 4; i++)
#pragma unroll
        for (int j = 0; j < 8; j++) acc[i][j] = 0.f;

    for (int kc = 0; kc < 256; kc += 32) {
#pragma unroll
        for (int i = 0; i < 8; i++) {            // As: 64r x 32k, k-major
            int flat = i * 256 + tid;
            int r = flat >> 5, k = flat & 31;
            int gr = rowBase + r;
            As[k * 68 + r] = (gr < M) ? A[(size_t)gr * 256 + kc + k] : 0.f;
        }
#pragma unroll
        for (int i = 0; i < 16; i++) {           // W1s: 32k x 128n
            int flat = i * 256 + tid;
            int k = flat >> 7, n = flat & 127;
            W1s[k * 132 + n] = W1[(size_t)(kc + k) * 128 + n];
        }
        __syncthreads();
#pragma unroll
        for (int k = 0; k < 32; k++) {
            float4 a  = *(const float4*)&As[k * 68 + r0];
            float4 b0 = *(const float4*)&W1s[k * 132 + c0];
            float4 b1v = *(const float4*)&W1s[k * 132 + c0 + 4];
            float av[4] = {a.x, a.y, a.z, a.w};
            float bv[8] = {b0.x, b0.y, b0.z, b0.w, b1v.x, b1v.y, b1v.z, b1v.w};
#pragma unroll
            for (int i = 0; i < 4; i++)
#pragma unroll
                for (int j = 0; j < 8; j++)
                    acc[i][j] += av[i] * bv[j];
        }
        __syncthreads();
    }

    // bias + relu, write E transposed (k-major) into Es
    float bb[8];
#pragma unroll
    for (int j = 0; j < 8; j++) bb[j] = b1[c0 + j];
    __syncthreads();
#pragma unroll
    for (int i = 0; i < 4; i++)
#pragma unroll
        for (int j = 0; j < 8; j++)
            Es[(c0 + j) * 68 + (r0 + i)] = fmaxf(acc[i][j] + bb[j], 0.f);
    __syncthreads();

    // ---- stage 2: Q[64][128] = E @ W2[128x128] ----
    float acc2[4][8];
#pragma unroll
    for (int i = 0; i < 4; i++)
#pragma unroll
        for (int j = 0; j < 8; j++) acc2[i][j] = 0.f;

    for (int kc = 0; kc < 128; kc += 32) {
#pragma unroll
        for (int i = 0; i < 16; i++) {
            int flat = i * 256 + tid;
            int k = flat >> 7, n = flat & 127;
            W2s[k * 132 + n] = W2[(size_t)(kc + k) * 128 + n];
        }
        __syncthreads();
#pragma unroll
        for (int k = 0; k < 32; k++) {
            float4 a  = *(const float4*)&Es[(kc + k) * 68 + r0];
            float4 b0 = *(const float4*)&W2s[k * 132 + c0];
            float4 b1v = *(const float4*)&W2s[k * 132 + c0 + 4];
            float av[4] = {a.x, a.y, a.z, a.w};
            float bv[8] = {b0.x, b0.y, b0.z, b0.w, b1v.x, b1v.y, b1v.z, b1v.w};
#pragma unroll
            for (int i = 0; i < 4; i++)
#pragma unroll
                for (int j = 0; j < 8; j++)
                    acc2[i][j] += av[i] * bv[j];
        }
        __syncthreads();
    }

    // ---- epilogue: per-head norms (head = c0>>5) + store Q ----
#pragma unroll
    for (int i = 0; i < 4; i++) {
        int gr = rowBase + r0 + i;
        float p = 0.f;
#pragma unroll
        for (int j = 0; j < 8; j++) p += acc2[i][j] * acc2[i][j];
        p += __shfl_xor(p, 1);
        p += __shfl_xor(p, 2);
        if (gr < M) {
            if ((cg & 3) == 0) norms[gr * 4 + (cg >> 2)] = sqrtf(p);
            *(float4*)(out + (size_t)gr * 128 + c0) =
                make_float4(acc2[i][0], acc2[i][1], acc2[i][2], acc2[i][3]);
            *(float4*)(out + (size_t)gr * 128 + c0 + 4) =
                make_float4(acc2[i][4], acc2[i][5], acc2[i][6], acc2[i][7]);
        }
    }
}

// ============ per-(undirected)-edge multi-head cosine mask ============
__global__ __launch_bounds__(256)
void edge_kernel(const int* __restrict__ ei, int Edir,
                 const float* __restrict__ Q, const float* __restrict__ Kf,
                 const float* __restrict__ qn, const float* __restrict__ kn,
                 const float* __restrict__ cwts,
                 float* __restrict__ maskf, int* __restrict__ cnt, int Eund)
{
    int gid = blockIdx.x * 256 + threadIdx.x;
    int e = gid >> 3;
    if (e >= Eund) return;
    int sub = gid & 7;
    int row = ei[e];
    int col = ei[Edir + e];
    row = min(max(row, 0), N_NUM - 1);
    col = min(max(col, 0), N_NUM - 1);
    int u  = (row < U_NUM) ? row : col;
    int fg = (row < U_NUM) ? col : row;
    u = min(max(u, 0), U_NUM - 1);
    int f = min(max(fg - U_NUM, 0), F_NUM - 1);

    const float4* qp = (const float4*)(Q  + (size_t)u * D_EMB + sub * 16);
    const float4* kp = (const float4*)(Kf + (size_t)f * D_EMB + sub * 16);
    float dot = 0.f;
#pragma unroll
    for (int i = 0; i < 4; i++) {
        float4 a = qp[i]; float4 b = kp[i];
        dot += a.x * b.x + a.y * b.y + a.z * b.z + a.w * b.w;
    }
    dot += __shfl_xor(dot, 1);           // 16+16 -> 32-elem head dot
    int h = sub >> 1;
    float denom = qn[u * 4 + h] * kn[f * 4 + h] + 1e-8f;
    float sim = dot / denom;
    float s = sim + __shfl_xor(sim, 2);  // pairs of heads
    s += __shfl_xor(s, 4);               // all 4 heads
    float mean = s * 0.25f;
    float mf = (mean > THRESH) ? 1.f : 0.f;

    float cw0 = cwts[0], cw1 = cwts[1];
    float mx = fmaxf(cw0, cw1);
    float e0 = expf(cw0 - mx), e1 = expf(cw1 - mx);
    float inv = 1.f / (e0 + e1);
    float fused = e0 * inv + (e1 * inv) * mf;
    float em = (fused > 0.5f) ? 1.f : 0.f;

    if (sub == 0) {
        maskf[e] = em;
        if (em != 0.f) {
            atomicAdd(&cnt[row], 1);
            atomicAdd(&cnt[col], 1);
        }
    }
}

// ============ exclusive scan over cnt[N] (3 kernels) ============
__global__ void scan_part(const int* __restrict__ cnt, int* __restrict__ part, int n)
{
    __shared__ int sd[256];
    int b = blockIdx.x, t = threadIdx.x;
    int base = b * 1024;
    int s = 0;
#pragma unroll
    for (int j = 0; j < 4; j++) {
        int idx = base + t + j * 256;
        if (idx < n) s += cnt[idx];
    }
    sd[t] = s; __syncthreads();
    for (int d = 128; d > 0; d >>= 1) {
        if (t < d) sd[t] += sd[t + d];
        __syncthreads();
    }
    if (t == 0) part[b] = sd[0];
}

__global__ void scan_small(int* part, int nb)
{
    __shared__ int sd[256];
    int t = threadIdx.x;
    sd[t] = (t < nb) ? part[t] : 0;
    __syncthreads();
    for (int d = 1; d < 256; d <<= 1) {
        int x = (t >= d) ? sd[t - d] : 0;
        __syncthreads();
        sd[t] += x;
        __syncthreads();
    }
    if (t < nb) part[t] = (t > 0) ? sd[t - 1] : 0;
}

__global__ void scan_final(const int* __restrict__ cnt, const int* __restrict__ part,
                           int* __restrict__ offs, int n)
{
    __shared__ int sd[256];
    int b = blockIdx.x, t = threadIdx.x;
    int base = b * 1024 + t * 4;
    int v[4]; int s = 0;
#pragma unroll
    for (int j = 0; j < 4; j++) {
        int idx = base + j;
        v[j] = (idx < n) ? cnt[idx] : 0;
        s += v[j];
    }
    sd[t] = s; __syncthreads();
    for (int d = 1; d < 256; d <<= 1) {
        int x = (t >= d) ? sd[t - d] : 0;
        __syncthreads();
        sd[t] += x;
        __syncthreads();
    }
    int prefix = part[b] + ((t > 0) ? sd[t - 1] : 0);
#pragma unroll
    for (int j = 0; j < 4; j++) {
        int idx = base + j;
        if (idx < n) offs[idx] = prefix;
        prefix += v[j];
    }
}

// ============ CSR scatter (both directions of each masked edge) ============
__global__ void scatter_kernel(const int* __restrict__ ei, int Edir,
                               const float* __restrict__ maskf,
                               const int* __restrict__ cnt, const int* __restrict__ offs,
                               int* __restrict__ cursor,
                               int* __restrict__ cnbr, float* __restrict__ cwA, int Eund)
{
    int e = blockIdx.x * 256 + threadIdx.x;
    if (e >= Eund) return;
    if (maskf[e] == 0.f) return;
    int row = ei[e], col = ei[Edir + e];
    row = min(max(row, 0), N_NUM - 1);
    col = min(max(col, 0), N_NUM - 1);
    float w = 1.0f / sqrtf((float)cnt[row] * (float)cnt[col]);
    int p1 = offs[row] + atomicAdd(&cursor[row], 1);
    cnbr[p1] = col; cwA[p1] = w;
    int p2 = offs[col] + atomicAdd(&cursor[col], 1);
    cnbr[p2] = row; cwA[p2] = w;
}

// ============ misc ============
__global__ void zero2(int* __restrict__ a, int* __restrict__ b, int n)
{
    int i = blockIdx.x * 256 + threadIdx.x;
    if (i < n) { a[i] = 0; b[i] = 0; }
}

// ============ propagation ============
// MODE 0: layer1 — gather x0 from embeds, write xout.
// MODE 1: middle — gather from xin, write xout.
// MODE 2: last   — gather x3 from xin; xout = (x0 + x1 + x2 + x3) * 0.25.
template<int MODE>
__global__ __launch_bounds__(256)
void prop(const int* __restrict__ offs, const int* __restrict__ cnt,
          const int* __restrict__ cnbr, const float* __restrict__ cwA,
          const float* __restrict__ xin,
          const float* __restrict__ ue, const float* __restrict__ ie,
          const float* __restrict__ x1b, float* __restrict__ xout)
{
    int wid = (blockIdx.x << 2) + (threadIdx.x >> 6);
    if (wid >= N_NUM) return;
    int lane = threadIdx.x & 63;
    int start = offs[wid], num = cnt[wid];
    float ax = 0.f, ay = 0.f;

    auto srcp = [&](int c) -> const float* {
        if (MODE == 0)
            return (c < U_NUM) ? (ue + (size_t)c * D_EMB) : (ie + (size_t)(c - U_NUM) * D_EMB);
        else
            return xin + (size_t)c * D_EMB;
    };

    int j = 0;
    for (; j + 4 <= num; j += 4) {
        int c0i = cnbr[start + j],     c1i = cnbr[start + j + 1];
        int c2i = cnbr[start + j + 2], c3i = cnbr[start + j + 3];
        float w0 = cwA[start + j],     w1 = cwA[start + j + 1];
        float w2 = cwA[start + j + 2], w3 = cwA[start + j + 3];
        float2 v0 = *(const float2*)(srcp(c0i) + lane * 2);
        float2 v1 = *(const float2*)(srcp(c1i) + lane * 2);
        float2 v2 = *(const float2*)(srcp(c2i) + lane * 2);
        float2 v3 = *(const float2*)(srcp(c3i) + lane * 2);
        ax += w0 * v0.x; ay += w0 * v0.y;
        ax += w1 * v1.x; ay += w1 * v1.y;
        ax += w2 * v2.x; ay += w2 * v2.y;
        ax += w3 * v3.x; ay += w3 * v3.y;
    }
    for (; j < num; ++j) {
        int c = cnbr[start + j]; float w = cwA[start + j];
        float2 v = *(const float2*)(srcp(c) + lane * 2);
        ax += w * v.x; ay += w * v.y;
    }

    size_t o = (size_t)wid * D_EMB + lane * 2;
    if (MODE == 2) {
        const float* x0p = (wid < U_NUM) ? (ue + (size_t)wid * D_EMB)
                                         : (ie + (size_t)(wid - U_NUM) * D_EMB);
        float2 x0v = *(const float2*)(x0p + lane * 2);
        float2 x1v = *(const float2*)(x1b + o);
        float2 x2v = *(const float2*)(xin + o);
        float ox = ((x0v.x + x1v.x) + x2v.x + ax) * 0.25f;
        float oy = ((x0v.y + x1v.y) + x2v.y + ay) * 0.25f;
        *(float2*)(xout + o) = make_float2(ox, oy);
    } else {
        *(float2*)(xout + o) = make_float2(ax, ay);
    }
}

__global__ void copy_embeds(const float* __restrict__ ue, const float* __restrict__ ie,
                            float* __restrict__ dst)
{
    int i = blockIdx.x * 256 + threadIdx.x;   // float4 index
    const int u4 = U_NUM * (D_EMB / 4);
    const int f4 = F_NUM * (D_EMB / 4);
    if (i < u4) ((float4*)dst)[i] = ((const float4*)ue)[i];
    else if (i < u4 + f4) ((float4*)dst)[i] = ((const float4*)ie)[i - u4];
}

// ============ launcher ============
extern "C" void kernel_launch(void* const* d_in, const int* in_sizes, int n_in,
                              void* d_out, int out_size, void* d_ws, size_t ws_size,
                              hipStream_t stream)
{
    const float* user_feat  = (const float*)d_in[0];
    const float* food_feat  = (const float*)d_in[1];
    const int*   ei         = (const int*)d_in[2];
    const float* W_user     = (const float*)d_in[3];
    const float* b_user     = (const float*)d_in[4];
    const float* W_food     = (const float*)d_in[5];
    const float* b_food     = (const float*)d_in[6];
    const float* Wq         = (const float*)d_in[7];
    const float* Wk         = (const float*)d_in[8];
    const float* cwts       = (const float*)d_in[9];
    const float* user_embed = (const float*)d_in[10];
    const float* item_embed = (const float*)d_in[11];

    const int Edir = in_sizes[2] / 2;   // 1.2M directed edges
    const int Eund = Edir / 2;          // 600K undirected ([u,f] || [f,u] structure)

    char* ws = (char*)d_ws;
    size_t off = 0;
    auto alloc = [&](size_t nb) { size_t o = off; off += (nb + 255) & ~(size_t)255; return o; };

    float* Q     = (float*)(ws + alloc((size_t)U_NUM * D_EMB * 4));  // Q|Kf contiguous -> xA
    float* Kf    = (float*)(ws + alloc((size_t)F_NUM * D_EMB * 4));
    float* qn    = (float*)(ws + alloc((size_t)U_NUM * 4 * 4));
    float* kn    = (float*)(ws + alloc((size_t)F_NUM * 4 * 4));
    float* xB    = (float*)(ws + alloc((size_t)N_NUM * D_EMB * 4));
    float* maskf = (float*)(ws + alloc((size_t)Eund * 4));
    int*   cnt   = (int*)  (ws + alloc((size_t)N_NUM * 4));
    int*   offs  = (int*)  (ws + alloc((size_t)N_NUM * 4));
    int*   cursor= (int*)  (ws + alloc((size_t)N_NUM * 4));
    int*   cnbr  = (int*)  (ws + alloc((size_t)Edir * 4));
    float* cwA   = (float*)(ws + alloc((size_t)Edir * 4));
    int*   part  = (int*)  (ws + alloc((size_t)256 * 4));
    (void)ws_size; (void)n_in; (void)out_size;

    float* xA = Q;   // N x 128, reuses Q|Kf after the edge stage

    // 1) zero counters
    zero2<<<(N_NUM + 255) / 256, 256, 0, stream>>>(cnt, cursor, N_NUM);

    // 2) fused projections (users + foods in one dispatch)
    const int nbU = (U_NUM + 63) / 64;   // 782
    const int nbF = (F_NUM + 63) / 64;   // 313
    fused_proj<<<nbU + nbF, 256, 0, stream>>>(user_feat, food_feat,
                                              W_user, b_user, W_food, b_food,
                                              Wq, Wk, Q, Kf, qn, kn, nbU);

    // 3) per-edge mask + degree counts
    edge_kernel<<<(Eund * 8 + 255) / 256, 256, 0, stream>>>(ei, Edir, Q, Kf, qn, kn, cwts,
                                                            maskf, cnt, Eund);

    // 4) exclusive scan of cnt -> offs
    int nb = (N_NUM + 1023) / 1024;
    scan_part <<<nb, 256, 0, stream>>>(cnt, part, N_NUM);
    scan_small<<<1, 256, 0, stream>>>(part, nb);
    scan_final<<<nb, 256, 0, stream>>>(cnt, part, offs, N_NUM);

    // 5) CSR scatter
    scatter_kernel<<<(Eund + 255) / 256, 256, 0, stream>>>(ei, Edir, maskf, cnt, offs,
                                                           cursor, cnbr, cwA, Eund);

    // 6) three LightGCN layers; x0 read straight from embeds, last layer fuses
    //    the (x0+x1+x2+x3)/4 epilogue into d_out's first half.
    int pb = (N_NUM + 3) / 4;
    prop<0><<<pb, 256, 0, stream>>>(offs, cnt, cnbr, cwA, nullptr, user_embed, item_embed,
                                    nullptr, xB);
    prop<1><<<pb, 256, 0, stream>>>(offs, cnt, cnbr, cwA, xB, user_embed, item_embed,
                                    nullptr, xA);
    prop<2><<<pb, 256, 0, stream>>>(offs, cnt, cnbr, cwA, xA, user_embed, item_embed,
                                    xB, (float*)d_out);

    // 7) embed copies into output tail
    copy_embeds<<<(N_NUM * (D_EMB / 4) + 255) / 256, 256, 0, stream>>>(
        user_embed, item_embed, (float*)d_out + (size_t)N_NUM * D_EMB);
}

// Round 4
// 224.407 us; speedup vs baseline: 2.4596x; 1.4069x over previous
//
#include <hip/hip_runtime.h>
#include <cstdint>

#define U_NUM 50000
#define F_NUM 20000
#define N_NUM 70000
#define D_EMB 128
#define THRESH 0.3f

typedef _Float16 half8 __attribute__((ext_vector_type(8)));
typedef float f32x4 __attribute__((ext_vector_type(4)));

// ============ pre-split weights into 2 fp16 planes, transposed [n][k] ============
// dst layout (ushort elems):
//  W1u: [0)        2 planes x [128n][256k]  (plane stride 32768)
//  W1f: [65536)    same
//  Wq : [131072)   2 planes x [128n][128k]  (plane stride 16384)
//  Wk : [163840)   same                      total 196608
__global__ void presplit(const float* __restrict__ Wu, const float* __restrict__ Wf,
                         const float* __restrict__ Wq, const float* __restrict__ Wk,
                         unsigned short* __restrict__ dst)
{
    int i = blockIdx.x * 256 + threadIdx.x;
    if (i >= 98304) return;
    float a; size_t d; int pstride;
    if (i < 32768) {
        int n = i >> 8, k = i & 255;
        a = Wu[k * 128 + n]; d = (size_t)n * 256 + k; pstride = 32768;
    } else if (i < 65536) {
        int j = i - 32768; int n = j >> 8, k = j & 255;
        a = Wf[k * 128 + n]; d = 65536 + (size_t)n * 256 + k; pstride = 32768;
    } else if (i < 81920) {
        int j = i - 65536; int n = j >> 7, k = j & 127;
        a = Wq[k * 128 + n]; d = 131072 + (size_t)n * 128 + k; pstride = 16384;
    } else {
        int j = i - 81920; int n = j >> 7, k = j & 127;
        a = Wk[k * 128 + n]; d = 163840 + (size_t)n * 128 + k; pstride = 16384;
    }
    _Float16 c1 = (_Float16)a;            // RNE
    float r = a - (float)c1;
    _Float16 c2 = (_Float16)r;            // RNE
    dst[d]           = __builtin_bit_cast(unsigned short, c1);
    dst[d + pstride] = __builtin_bit_cast(unsigned short, c2);
}

// ============ split 8 f32 -> hi/lo fp16 fragments (RNE scalar casts) ============
__device__ __forceinline__ void split2(const float4 x0, const float4 x1,
                                       half8& h, half8& lo)
{
    float v[8] = {x0.x, x0.y, x0.z, x0.w, x1.x, x1.y, x1.z, x1.w};
#pragma unroll
    for (int i = 0; i < 8; i++) {
        _Float16 c1 = (_Float16)v[i];
        h[i] = c1;
        lo[i] = (_Float16)(v[i] - (float)c1);
    }
}

// ============ fused projection via split-fp16 MFMA ============
// Q = relu(A[Mx256] @ W1 + b1) @ W2, all effectively f32-accurate.
// 128 threads = 2 waves; wave owns 64 rows x 128 cols; block = 128 rows.
// No __syncthreads: E lives in per-wave LDS region (f32, XOR-swizzled).
__global__ __launch_bounds__(128)
void fused_proj_mfma(const float* __restrict__ uf, const float* __restrict__ ff,
                     const unsigned short* __restrict__ Wsp,
                     const float* __restrict__ bu, const float* __restrict__ bfo,
                     float* __restrict__ Qo, float* __restrict__ Ko, int nbU)
{
    __shared__ float Elds[16384];   // 64 KB: 2 waves x 64 rows x 128 f32 (swizzled)

    const int bid = blockIdx.x;
    const bool isU = bid < nbU;
    const float* A  = isU ? uf : ff;
    const float* b1 = isU ? bu : bfo;
    const unsigned short* W1 = Wsp + (isU ? 0 : 65536);
    const unsigned short* W2 = Wsp + (isU ? 131072 : 163840);
    const int W2p = 16384, W1p = 32768;
    float* out = isU ? Qo : Ko;
    const int M = isU ? U_NUM : F_NUM;
    const int rowBase = (isU ? bid : bid - nbU) * 128;

    const int tid = threadIdx.x;
    const int w  = tid >> 6;
    const int l  = tid & 63;
    const int lm = l & 15;       // m/n index within fragment
    const int lq = l >> 4;       // k-group
    const int wrow = rowBase + w * 64;
    float* EW = Elds + w * 8192; // this wave's 32KB E region

    f32x4 acc[4][8];
#pragma unroll
    for (int i = 0; i < 4; i++)
#pragma unroll
        for (int j = 0; j < 8; j++) acc[i][j] = (f32x4)0.f;

    // ---- stage 1: E = relu(A @ W1 + b1), K=256 in 8 chunks of 32 ----
    for (int kc = 0; kc < 8; ++kc) {
        half8 a1[4], a2[4];
#pragma unroll
        for (int rb = 0; rb < 4; ++rb) {
            int r = wrow + rb * 16 + lm;
            r = min(r, M - 1);
            const float4* ap = (const float4*)(A + (size_t)r * 256 + kc * 32 + lq * 8);
            split2(ap[0], ap[1], a1[rb], a2[rb]);
        }
#pragma unroll
        for (int cb = 0; cb < 8; ++cb) {
            size_t bo = (size_t)(cb * 16 + lm) * 256 + kc * 32 + lq * 8;
            half8 bh = *(const half8*)(W1 + bo);
            half8 bl = *(const half8*)(W1 + W1p + bo);
#pragma unroll
            for (int rb = 0; rb < 4; ++rb) {
                acc[rb][cb] = __builtin_amdgcn_mfma_f32_16x16x32_f16(a2[rb], bl, acc[rb][cb], 0, 0, 0);
                acc[rb][cb] = __builtin_amdgcn_mfma_f32_16x16x32_f16(a2[rb], bh, acc[rb][cb], 0, 0, 0);
                acc[rb][cb] = __builtin_amdgcn_mfma_f32_16x16x32_f16(a1[rb], bl, acc[rb][cb], 0, 0, 0);
                acc[rb][cb] = __builtin_amdgcn_mfma_f32_16x16x32_f16(a1[rb], bh, acc[rb][cb], 0, 0, 0);
            }
        }
    }

    // ---- bias + relu -> E into LDS (f32, 16B-chunk XOR swizzle by row&7) ----
#pragma unroll
    for (int cb = 0; cb < 8; ++cb) {
        int col = cb * 16 + lm;
        float bb = b1[col];
#pragma unroll
        for (int rb = 0; rb < 4; ++rb)
#pragma unroll
            for (int rg = 0; rg < 4; ++rg) {
                int row = rb * 16 + lq * 4 + rg;
                float e = fmaxf(acc[rb][cb][rg] + bb, 0.f);
                EW[row * 128 + (((col >> 2) ^ (row & 7)) << 2) + (col & 3)] = e;
            }
    }

#pragma unroll
    for (int i = 0; i < 4; i++)
#pragma unroll
        for (int j = 0; j < 8; j++) acc[i][j] = (f32x4)0.f;

    // ---- stage 2: Q = E @ W2, K=128 in 4 chunks of 32 ----
    for (int kc = 0; kc < 4; ++kc) {
        half8 a1[4], a2[4];
#pragma unroll
        for (int rb = 0; rb < 4; ++rb) {
            int row = rb * 16 + lm;
            int r7 = row & 7;
            int c0 = kc * 8 + lq * 2;             // even 16B-chunk index
            const float* base = EW + row * 128;
            float4 x0 = *(const float4*)(base + ((c0 ^ r7) << 2));
            float4 x1 = *(const float4*)(base + (((c0 + 1) ^ r7) << 2));
            split2(x0, x1, a1[rb], a2[rb]);
        }
#pragma unroll
        for (int cb = 0; cb < 8; ++cb) {
            size_t bo = (size_t)(cb * 16 + lm) * 128 + kc * 32 + lq * 8;
            half8 bh = *(const half8*)(W2 + bo);
            half8 bl = *(const half8*)(W2 + W2p + bo);
#pragma unroll
            for (int rb = 0; rb < 4; ++rb) {
                acc[rb][cb] = __builtin_amdgcn_mfma_f32_16x16x32_f16(a2[rb], bl, acc[rb][cb], 0, 0, 0);
                acc[rb][cb] = __builtin_amdgcn_mfma_f32_16x16x32_f16(a2[rb], bh, acc[rb][cb], 0, 0, 0);
                acc[rb][cb] = __builtin_amdgcn_mfma_f32_16x16x32_f16(a1[rb], bl, acc[rb][cb], 0, 0, 0);
                acc[rb][cb] = __builtin_amdgcn_mfma_f32_16x16x32_f16(a1[rb], bh, acc[rb][cb], 0, 0, 0);
            }
        }
    }

    // ---- store Q ----
#pragma unroll
    for (int cb = 0; cb < 8; ++cb)
#pragma unroll
        for (int rb = 0; rb < 4; ++rb)
#pragma unroll
            for (int rg = 0; rg < 4; ++rg) {
                int r = wrow + rb * 16 + lq * 4 + rg;
                if (r < M) out[(size_t)r * 128 + cb * 16 + lm] = acc[rb][cb][rg];
            }
}

// ============ per-(undirected)-edge multi-head cosine mask (norms in-kernel) ============
__global__ __launch_bounds__(256)
void edge_kernel(const int* __restrict__ ei, int Edir,
                 const float* __restrict__ Q, const float* __restrict__ Kf,
                 const float* __restrict__ cwts,
                 float* __restrict__ maskf, int* __restrict__ cnt, int Eund)
{
    int gid = blockIdx.x * 256 + threadIdx.x;
    int e = gid >> 3;
    if (e >= Eund) return;
    int sub = gid & 7;
    int row = ei[e];
    int col = ei[Edir + e];
    row = min(max(row, 0), N_NUM - 1);
    col = min(max(col, 0), N_NUM - 1);
    int u  = (row < U_NUM) ? row : col;
    int fg = (row < U_NUM) ? col : row;
    u = min(max(u, 0), U_NUM - 1);
    int f = min(max(fg - U_NUM, 0), F_NUM - 1);

    const float4* qp = (const float4*)(Q  + (size_t)u * D_EMB + sub * 16);
    const float4* kp = (const float4*)(Kf + (size_t)f * D_EMB + sub * 16);
    float dot = 0.f, qq = 0.f, kk = 0.f;
#pragma unroll
    for (int i = 0; i < 4; i++) {
        float4 a = qp[i]; float4 b = kp[i];
        dot += a.x * b.x + a.y * b.y + a.z * b.z + a.w * b.w;
        qq  += a.x * a.x + a.y * a.y + a.z * a.z + a.w * a.w;
        kk  += b.x * b.x + b.y * b.y + b.z * b.z + b.w * b.w;
    }
    dot += __shfl_xor(dot, 1);           // 16+16 -> 32-elem head reductions
    qq  += __shfl_xor(qq, 1);
    kk  += __shfl_xor(kk, 1);
    float denom = sqrtf(qq) * sqrtf(kk) + 1e-8f;
    float sim = dot / denom;
    float s = sim + __shfl_xor(sim, 2);  // pairs of heads
    s += __shfl_xor(s, 4);               // all 4 heads
    float mean = s * 0.25f;
    float mf = (mean > THRESH) ? 1.f : 0.f;

    float cw0 = cwts[0], cw1 = cwts[1];
    float mx = fmaxf(cw0, cw1);
    float e0 = expf(cw0 - mx), e1 = expf(cw1 - mx);
    float inv = 1.f / (e0 + e1);
    float fused = e0 * inv + (e1 * inv) * mf;
    float em = (fused > 0.5f) ? 1.f : 0.f;

    if (sub == 0) {
        maskf[e] = em;
        if (em != 0.f) {
            atomicAdd(&cnt[row], 1);
            atomicAdd(&cnt[col], 1);
        }
    }
}

// ============ exclusive scan over cnt[N] (3 kernels) ============
__global__ void scan_part(const int* __restrict__ cnt, int* __restrict__ part, int n)
{
    __shared__ int sd[256];
    int b = blockIdx.x, t = threadIdx.x;
    int base = b * 1024;
    int s = 0;
#pragma unroll
    for (int j = 0; j < 4; j++) {
        int idx = base + t + j * 256;
        if (idx < n) s += cnt[idx];
    }
    sd[t] = s; __syncthreads();
    for (int d = 128; d > 0; d >>= 1) {
        if (t < d) sd[t] += sd[t + d];
        __syncthreads();
    }
    if (t == 0) part[b] = sd[0];
}

__global__ void scan_small(int* part, int nb)
{
    __shared__ int sd[256];
    int t = threadIdx.x;
    sd[t] = (t < nb) ? part[t] : 0;
    __syncthreads();
    for (int d = 1; d < 256; d <<= 1) {
        int x = (t >= d) ? sd[t - d] : 0;
        __syncthreads();
        sd[t] += x;
        __syncthreads();
    }
    if (t < nb) part[t] = (t > 0) ? sd[t - 1] : 0;
}

__global__ void scan_final(const int* __restrict__ cnt, const int* __restrict__ part,
                           int* __restrict__ offs, int n)
{
    __shared__ int sd[256];
    int b = blockIdx.x, t = threadIdx.x;
    int base = b * 1024 + t * 4;
    int v[4]; int s = 0;
#pragma unroll
    for (int j = 0; j < 4; j++) {
        int idx = base + j;
        v[j] = (idx < n) ? cnt[idx] : 0;
        s += v[j];
    }
    sd[t] = s; __syncthreads();
    for (int d = 1; d < 256; d <<= 1) {
        int x = (t >= d) ? sd[t - d] : 0;
        __syncthreads();
        sd[t] += x;
        __syncthreads();
    }
    int prefix = part[b] + ((t > 0) ? sd[t - 1] : 0);
#pragma unroll
    for (int j = 0; j < 4; j++) {
        int idx = base + j;
        if (idx < n) offs[idx] = prefix;
        prefix += v[j];
    }
}

// ============ CSR scatter ============
__global__ void scatter_kernel(const int* __restrict__ ei, int Edir,
                               const float* __restrict__ maskf,
                               const int* __restrict__ cnt, const int* __restrict__ offs,
                               int* __restrict__ cursor,
                               int* __restrict__ cnbr, float* __restrict__ cwA, int Eund)
{
    int e = blockIdx.x * 256 + threadIdx.x;
    if (e >= Eund) return;
    if (maskf[e] == 0.f) return;
    int row = ei[e], col = ei[Edir + e];
    row = min(max(row, 0), N_NUM - 1);
    col = min(max(col, 0), N_NUM - 1);
    float w = 1.0f / sqrtf((float)cnt[row] * (float)cnt[col]);
    int p1 = offs[row] + atomicAdd(&cursor[row], 1);
    cnbr[p1] = col; cwA[p1] = w;
    int p2 = offs[col] + atomicAdd(&cursor[col], 1);
    cnbr[p2] = row; cwA[p2] = w;
}

// ============ misc ============
__global__ void zero2(int* __restrict__ a, int* __restrict__ b, int n)
{
    int i = blockIdx.x * 256 + threadIdx.x;
    if (i < n) { a[i] = 0; b[i] = 0; }
}

// ============ propagation ============
template<int MODE>
__global__ __launch_bounds__(256)
void prop(const int* __restrict__ offs, const int* __restrict__ cnt,
          const int* __restrict__ cnbr, const float* __restrict__ cwA,
          const float* __restrict__ xin,
          const float* __restrict__ ue, const float* __restrict__ ie,
          const float* __restrict__ x1b, float* __restrict__ xout)
{
    int wid = (blockIdx.x << 2) + (threadIdx.x >> 6);
    if (wid >= N_NUM) return;
    int lane = threadIdx.x & 63;
    int start = offs[wid], num = cnt[wid];
    float ax = 0.f, ay = 0.f;

    auto srcp = [&](int c) -> const float* {
        if (MODE == 0)
            return (c < U_NUM) ? (ue + (size_t)c * D_EMB) : (ie + (size_t)(c - U_NUM) * D_EMB);
        else
            return xin + (size_t)c * D_EMB;
    };

    int j = 0;
    for (; j + 4 <= num; j += 4) {
        int c0i = cnbr[start + j],     c1i = cnbr[start + j + 1];
        int c2i = cnbr[start + j + 2], c3i = cnbr[start + j + 3];
        float w0 = cwA[start + j],     w1 = cwA[start + j + 1];
        float w2 = cwA[start + j + 2], w3 = cwA[start + j + 3];
        float2 v0 = *(const float2*)(srcp(c0i) + lane * 2);
        float2 v1 = *(const float2*)(srcp(c1i) + lane * 2);
        float2 v2 = *(const float2*)(srcp(c2i) + lane * 2);
        float2 v3 = *(const float2*)(srcp(c3i) + lane * 2);
        ax += w0 * v0.x; ay += w0 * v0.y;
        ax += w1 * v1.x; ay += w1 * v1.y;
        ax += w2 * v2.x; ay += w2 * v2.y;
        ax += w3 * v3.x; ay += w3 * v3.y;
    }
    for (; j < num; ++j) {
        int c = cnbr[start + j]; float w = cwA[start + j];
        float2 v = *(const float2*)(srcp(c) + lane * 2);
        ax += w * v.x; ay += w * v.y;
    }

    size_t o = (size_t)wid * D_EMB + lane * 2;
    if (MODE == 2) {
        const float* x0p = (wid < U_NUM) ? (ue + (size_t)wid * D_EMB)
                                         : (ie + (size_t)(wid - U_NUM) * D_EMB);
        float2 x0v = *(const float2*)(x0p + lane * 2);
        float2 x1v = *(const float2*)(x1b + o);
        float2 x2v = *(const float2*)(xin + o);
        float ox = ((x0v.x + x1v.x) + x2v.x + ax) * 0.25f;
        float oy = ((x0v.y + x1v.y) + x2v.y + ay) * 0.25f;
        *(float2*)(xout + o) = make_float2(ox, oy);
    } else {
        *(float2*)(xout + o) = make_float2(ax, ay);
    }
}

__global__ void copy_embeds(const float* __restrict__ ue, const float* __restrict__ ie,
                            float* __restrict__ dst)
{
    int i = blockIdx.x * 256 + threadIdx.x;   // float4 index
    const int u4 = U_NUM * (D_EMB / 4);
    const int f4 = F_NUM * (D_EMB / 4);
    if (i < u4) ((float4*)dst)[i] = ((const float4*)ue)[i];
    else if (i < u4 + f4) ((float4*)dst)[i] = ((const float4*)ie)[i - u4];
}

// ============ launcher ============
extern "C" void kernel_launch(void* const* d_in, const int* in_sizes, int n_in,
                              void* d_out, int out_size, void* d_ws, size_t ws_size,
                              hipStream_t stream)
{
    const float* user_feat  = (const float*)d_in[0];
    const float* food_feat  = (const float*)d_in[1];
    const int*   ei         = (const int*)d_in[2];
    const float* W_user     = (const float*)d_in[3];
    const float* b_user     = (const float*)d_in[4];
    const float* W_food     = (const float*)d_in[5];
    const float* b_food     = (const float*)d_in[6];
    const float* Wq         = (const float*)d_in[7];
    const float* Wk         = (const float*)d_in[8];
    const float* cwts       = (const float*)d_in[9];
    const float* user_embed = (const float*)d_in[10];
    const float* item_embed = (const float*)d_in[11];

    const int Edir = in_sizes[2] / 2;   // 1.2M directed edges
    const int Eund = Edir / 2;          // 600K undirected ([u,f] || [f,u])

    char* ws = (char*)d_ws;
    size_t off = 0;
    auto alloc = [&](size_t nb) { size_t o = off; off += (nb + 255) & ~(size_t)255; return o; };

    float* Q     = (float*)(ws + alloc((size_t)U_NUM * D_EMB * 4));  // Q|Kf contiguous -> xA
    float* Kf    = (float*)(ws + alloc((size_t)F_NUM * D_EMB * 4));
    float* xB    = (float*)(ws + alloc((size_t)N_NUM * D_EMB * 4));
    float* maskf = (float*)(ws + alloc((size_t)Eund * 4));
    int*   cnt   = (int*)  (ws + alloc((size_t)N_NUM * 4));
    int*   offs  = (int*)  (ws + alloc((size_t)N_NUM * 4));
    int*   cursor= (int*)  (ws + alloc((size_t)N_NUM * 4));
    int*   cnbr  = (int*)  (ws + alloc((size_t)Edir * 4));
    float* cwA   = (float*)(ws + alloc((size_t)Edir * 4));
    int*   part  = (int*)  (ws + alloc((size_t)256 * 4));
    unsigned short* Wsp = (unsigned short*)(ws + alloc((size_t)196608 * 2));
    (void)ws_size; (void)n_in; (void)out_size;

    float* xA = Q;   // N x 128, reuses Q|Kf after the edge stage

    // 1) zero counters + pre-split weights
    zero2<<<(N_NUM + 255) / 256, 256, 0, stream>>>(cnt, cursor, N_NUM);
    presplit<<<384, 256, 0, stream>>>(W_user, W_food, Wq, Wk, Wsp);

    // 2) fused projections via split-fp16 MFMA
    const int nbU = (U_NUM + 127) / 128;   // 391
    const int nbF = (F_NUM + 127) / 128;   // 157
    fused_proj_mfma<<<nbU + nbF, 128, 0, stream>>>(user_feat, food_feat, Wsp,
                                                   b_user, b_food, Q, Kf, nbU);

    // 3) per-edge mask + degree counts
    edge_kernel<<<(Eund * 8 + 255) / 256, 256, 0, stream>>>(ei, Edir, Q, Kf, cwts,
                                                            maskf, cnt, Eund);

    // 4) exclusive scan of cnt -> offs
    int nb = (N_NUM + 1023) / 1024;
    scan_part <<<nb, 256, 0, stream>>>(cnt, part, N_NUM);
    scan_small<<<1, 256, 0, stream>>>(part, nb);
    scan_final<<<nb, 256, 0, stream>>>(cnt, part, offs, N_NUM);

    // 5) CSR scatter
    scatter_kernel<<<(Eund + 255) / 256, 256, 0, stream>>>(ei, Edir, maskf, cnt, offs,
                                                           cursor, cnbr, cwA, Eund);

    // 6) three LightGCN layers; last fuses the (x0+x1+x2+x3)/4 epilogue
    int pb = (N_NUM + 3) / 4;
    prop<0><<<pb, 256, 0, stream>>>(offs, cnt, cnbr, cwA, nullptr, user_embed, item_embed,
                                    nullptr, xB);
    prop<1><<<pb, 256, 0, stream>>>(offs, cnt, cnbr, cwA, xB, user_embed, item_embed,
                                    nullptr, xA);
    prop<2><<<pb, 256, 0, stream>>>(offs, cnt, cnbr, cwA, xA, user_embed, item_embed,
                                    xB, (float*)d_out);

    // 7) embed copies into output tail
    copy_embeds<<<(N_NUM * (D_EMB / 4) + 255) / 256, 256, 0, stream>>>(
        user_embed, item_embed, (float*)d_out + (size_t)N_NUM * D_EMB);
}

// Round 5
// 208.366 us; speedup vs baseline: 2.6490x; 1.0770x over previous
//
#include <hip/hip_runtime.h>
#include <cstdint>

#define U_NUM 50000
#define F_NUM 20000
#define N_NUM 70000
#define D_EMB 128
#define THRESH 0.3f

typedef _Float16 half8 __attribute__((ext_vector_type(8)));
typedef float f32x4 __attribute__((ext_vector_type(4)));

// ============ pre-split weights (2 fp16 planes, transposed [n][k]) + zero counters ============
// dst layout (ushort elems):
//  W1u: [0)        2 planes x [128n][256k]  (plane stride 32768)
//  W1f: [65536)    same
//  Wq : [131072)   2 planes x [128n][128k]  (plane stride 16384)
//  Wk : [163840)   same                      total 196608
__global__ void presplit_zero(const float* __restrict__ Wu, const float* __restrict__ Wf,
                              const float* __restrict__ Wq, const float* __restrict__ Wk,
                              unsigned short* __restrict__ dst,
                              int* __restrict__ cnt, int* __restrict__ cursor)
{
    int i = blockIdx.x * 256 + threadIdx.x;
    if (i < N_NUM) { cnt[i] = 0; cursor[i] = 0; }
    if (i >= 98304) return;
    float a; size_t d; int pstride;
    if (i < 32768) {
        int n = i >> 8, k = i & 255;
        a = Wu[k * 128 + n]; d = (size_t)n * 256 + k; pstride = 32768;
    } else if (i < 65536) {
        int j = i - 32768; int n = j >> 8, k = j & 255;
        a = Wf[k * 128 + n]; d = 65536 + (size_t)n * 256 + k; pstride = 32768;
    } else if (i < 81920) {
        int j = i - 65536; int n = j >> 7, k = j & 127;
        a = Wq[k * 128 + n]; d = 131072 + (size_t)n * 128 + k; pstride = 16384;
    } else {
        int j = i - 81920; int n = j >> 7, k = j & 127;
        a = Wk[k * 128 + n]; d = 163840 + (size_t)n * 128 + k; pstride = 16384;
    }
    _Float16 c1 = (_Float16)a;            // RNE
    float r = a - (float)c1;
    _Float16 c2 = (_Float16)r;            // RNE
    dst[d]           = __builtin_bit_cast(unsigned short, c1);
    dst[d + pstride] = __builtin_bit_cast(unsigned short, c2);
}

// ============ split 8 f32 -> hi/lo fp16 fragments (RNE scalar casts) ============
__device__ __forceinline__ void split2(const float4 x0, const float4 x1,
                                       half8& h, half8& lo)
{
    float v[8] = {x0.x, x0.y, x0.z, x0.w, x1.x, x1.y, x1.z, x1.w};
#pragma unroll
    for (int i = 0; i < 8; i++) {
        _Float16 c1 = (_Float16)v[i];
        h[i] = c1;
        lo[i] = (_Float16)(v[i] - (float)c1);
    }
}

// ============ fused projection via split-fp16 MFMA (3-product) ============
// Q = relu(A[Mx256] @ W1 + b1) @ W2.  256 thr = 4 waves, 32 rows/wave.
// E staged per-wave in 4KB LDS chunks (32 rows x 32 cols f32, XOR-swizzled),
// one chunk per stage-2 k-step -> 16KB LDS/block, no barriers (wave-private).
__global__ __launch_bounds__(256, 2)
void fused_proj_mfma(const float* __restrict__ uf, const float* __restrict__ ff,
                     const unsigned short* __restrict__ Wsp,
                     const float* __restrict__ bu, const float* __restrict__ bfo,
                     float* __restrict__ Qo, float* __restrict__ Ko, int nbU)
{
    __shared__ float Elds[4096];   // 16 KB

    const int bid = blockIdx.x;
    const bool isU = bid < nbU;
    const float* A  = isU ? uf : ff;
    const float* b1 = isU ? bu : bfo;
    const unsigned short* W1 = Wsp + (isU ? 0 : 65536);
    const unsigned short* W2 = Wsp + (isU ? 131072 : 163840);
    const int W1p = 32768, W2p = 16384;
    float* out = isU ? Qo : Ko;
    const int M = isU ? U_NUM : F_NUM;
    const int rowBase = (isU ? bid : bid - nbU) * 128;

    const int tid = threadIdx.x;
    const int w  = tid >> 6;
    const int l  = tid & 63;
    const int lm = l & 15;       // m/n index within fragment
    const int lq = l >> 4;       // k-group
    const int wrow = rowBase + w * 32;
    float* EW = Elds + w * 1024; // this wave's 4KB chunk

    f32x4 acc1[2][8];
#pragma unroll
    for (int i = 0; i < 2; i++)
#pragma unroll
        for (int j = 0; j < 8; j++) acc1[i][j] = (f32x4)0.f;

    // ---- stage 1: E = A @ W1 (bias/relu deferred), K=256 in 8 chunks ----
    for (int kc = 0; kc < 8; ++kc) {
        half8 a1[2], a2[2];
#pragma unroll
        for (int rb = 0; rb < 2; ++rb) {
            int r = wrow + rb * 16 + lm;
            r = min(r, M - 1);
            const float4* ap = (const float4*)(A + (size_t)r * 256 + kc * 32 + lq * 8);
            split2(ap[0], ap[1], a1[rb], a2[rb]);
        }
#pragma unroll
        for (int cb = 0; cb < 8; ++cb) {
            size_t bo = (size_t)(cb * 16 + lm) * 256 + kc * 32 + lq * 8;
            half8 bh = *(const half8*)(W1 + bo);
            half8 bl = *(const half8*)(W1 + W1p + bo);
#pragma unroll
            for (int rb = 0; rb < 2; ++rb) {
                acc1[rb][cb] = __builtin_amdgcn_mfma_f32_16x16x32_f16(a2[rb], bh, acc1[rb][cb], 0, 0, 0);
                acc1[rb][cb] = __builtin_amdgcn_mfma_f32_16x16x32_f16(a1[rb], bl, acc1[rb][cb], 0, 0, 0);
                acc1[rb][cb] = __builtin_amdgcn_mfma_f32_16x16x32_f16(a1[rb], bh, acc1[rb][cb], 0, 0, 0);
            }
        }
    }

    f32x4 acc2[2][8];
#pragma unroll
    for (int i = 0; i < 2; i++)
#pragma unroll
        for (int j = 0; j < 8; j++) acc2[i][j] = (f32x4)0.f;

    // ---- stage 2: Q = relu(E+b1) @ W2, chunked through 4KB LDS ----
#pragma unroll
    for (int kc2 = 0; kc2 < 4; ++kc2) {
        // write E cols [kc2*32, kc2*32+32) with bias+relu, 16B-chunk XOR swizzle
#pragma unroll
        for (int cbh = 0; cbh < 2; ++cbh) {
            const int cb = kc2 * 2 + cbh;
            const int col = cbh * 16 + lm;                 // local col 0..31
            const float bb = b1[kc2 * 32 + col];
#pragma unroll
            for (int rb = 0; rb < 2; ++rb)
#pragma unroll
                for (int rg = 0; rg < 4; ++rg) {
                    const int row = rb * 16 + lq * 4 + rg;
                    float e = fmaxf(acc1[rb][cb][rg] + bb, 0.f);
                    EW[row * 32 + ((((col >> 2) ^ (row & 7)) << 2) | (col & 3))] = e;
                }
        }
        // read back as A-fragments (wave-private LDS, in-order DS pipe -> no barrier)
        half8 ea1[2], ea2[2];
#pragma unroll
        for (int rb = 0; rb < 2; ++rb) {
            const int row = rb * 16 + lm;
            const int r7 = row & 7;
            const float* base = EW + row * 32;
            float4 x0 = *(const float4*)(base + (((lq * 2)     ^ r7) << 2));
            float4 x1 = *(const float4*)(base + (((lq * 2 + 1) ^ r7) << 2));
            split2(x0, x1, ea1[rb], ea2[rb]);
        }
#pragma unroll
        for (int cb2 = 0; cb2 < 8; ++cb2) {
            size_t bo = (size_t)(cb2 * 16 + lm) * 128 + kc2 * 32 + lq * 8;
            half8 bh = *(const half8*)(W2 + bo);
            half8 bl = *(const half8*)(W2 + W2p + bo);
#pragma unroll
            for (int rb = 0; rb < 2; ++rb) {
                acc2[rb][cb2] = __builtin_amdgcn_mfma_f32_16x16x32_f16(ea2[rb], bh, acc2[rb][cb2], 0, 0, 0);
                acc2[rb][cb2] = __builtin_amdgcn_mfma_f32_16x16x32_f16(ea1[rb], bl, acc2[rb][cb2], 0, 0, 0);
                acc2[rb][cb2] = __builtin_amdgcn_mfma_f32_16x16x32_f16(ea1[rb], bh, acc2[rb][cb2], 0, 0, 0);
            }
        }
    }

    // ---- store Q ----
#pragma unroll
    for (int cb2 = 0; cb2 < 8; ++cb2)
#pragma unroll
        for (int rb = 0; rb < 2; ++rb)
#pragma unroll
            for (int rg = 0; rg < 4; ++rg) {
                int r = wrow + rb * 16 + lq * 4 + rg;
                if (r < M) out[(size_t)r * 128 + cb2 * 16 + lm] = acc2[rb][cb2][rg];
            }
}

// ============ per-(undirected)-edge multi-head cosine mask ============
__global__ __launch_bounds__(256)
void edge_kernel(const int* __restrict__ ei, int Edir,
                 const float* __restrict__ Q, const float* __restrict__ Kf,
                 const float* __restrict__ cwts,
                 float* __restrict__ maskf, int* __restrict__ cnt, int Eund)
{
    int gid = blockIdx.x * 256 + threadIdx.x;
    int e = gid >> 3;
    if (e >= Eund) return;
    int sub = gid & 7;
    int row = ei[e];
    int col = ei[Edir + e];
    row = min(max(row, 0), N_NUM - 1);
    col = min(max(col, 0), N_NUM - 1);
    int u  = (row < U_NUM) ? row : col;
    int fg = (row < U_NUM) ? col : row;
    u = min(max(u, 0), U_NUM - 1);
    int f = min(max(fg - U_NUM, 0), F_NUM - 1);

    const float4* qp = (const float4*)(Q  + (size_t)u * D_EMB + sub * 16);
    const float4* kp = (const float4*)(Kf + (size_t)f * D_EMB + sub * 16);
    float dot = 0.f, qq = 0.f, kk = 0.f;
#pragma unroll
    for (int i = 0; i < 4; i++) {
        float4 a = qp[i]; float4 b = kp[i];
        dot += a.x * b.x + a.y * b.y + a.z * b.z + a.w * b.w;
        qq  += a.x * a.x + a.y * a.y + a.z * a.z + a.w * a.w;
        kk  += b.x * b.x + b.y * b.y + b.z * b.z + b.w * b.w;
    }
    dot += __shfl_xor(dot, 1);           // 16+16 -> 32-elem head reductions
    qq  += __shfl_xor(qq, 1);
    kk  += __shfl_xor(kk, 1);
    float denom = sqrtf(qq) * sqrtf(kk) + 1e-8f;
    float sim = dot / denom;
    float s = sim + __shfl_xor(sim, 2);  // pairs of heads
    s += __shfl_xor(s, 4);               // all 4 heads
    float mean = s * 0.25f;
    float mf = (mean > THRESH) ? 1.f : 0.f;

    float cw0 = cwts[0], cw1 = cwts[1];
    float mx = fmaxf(cw0, cw1);
    float e0 = expf(cw0 - mx), e1 = expf(cw1 - mx);
    float inv = 1.f / (e0 + e1);
    float fused = e0 * inv + (e1 * inv) * mf;
    float em = (fused > 0.5f) ? 1.f : 0.f;

    if (sub == 0) {
        maskf[e] = em;
        if (em != 0.f) {
            atomicAdd(&cnt[row], 1);
            atomicAdd(&cnt[col], 1);
        }
    }
}

// ============ exclusive scan over cnt[N] (3 kernels) ============
__global__ void scan_part(const int* __restrict__ cnt, int* __restrict__ part, int n)
{
    __shared__ int sd[256];
    int b = blockIdx.x, t = threadIdx.x;
    int base = b * 1024;
    int s = 0;
#pragma unroll
    for (int j = 0; j < 4; j++) {
        int idx = base + t + j * 256;
        if (idx < n) s += cnt[idx];
    }
    sd[t] = s; __syncthreads();
    for (int d = 128; d > 0; d >>= 1) {
        if (t < d) sd[t] += sd[t + d];
        __syncthreads();
    }
    if (t == 0) part[b] = sd[0];
}

__global__ void scan_small(int* part, int nb)
{
    __shared__ int sd[256];
    int t = threadIdx.x;
    sd[t] = (t < nb) ? part[t] : 0;
    __syncthreads();
    for (int d = 1; d < 256; d <<= 1) {
        int x = (t >= d) ? sd[t - d] : 0;
        __syncthreads();
        sd[t] += x;
        __syncthreads();
    }
    if (t < nb) part[t] = (t > 0) ? sd[t - 1] : 0;
}

__global__ void scan_final(const int* __restrict__ cnt, const int* __restrict__ part,
                           int* __restrict__ offs, int n)
{
    __shared__ int sd[256];
    int b = blockIdx.x, t = threadIdx.x;
    int base = b * 1024 + t * 4;
    int v[4]; int s = 0;
#pragma unroll
    for (int j = 0; j < 4; j++) {
        int idx = base + j;
        v[j] = (idx < n) ? cnt[idx] : 0;
        s += v[j];
    }
    sd[t] = s; __syncthreads();
    for (int d = 1; d < 256; d <<= 1) {
        int x = (t >= d) ? sd[t - d] : 0;
        __syncthreads();
        sd[t] += x;
        __syncthreads();
    }
    int prefix = part[b] + ((t > 0) ? sd[t - 1] : 0);
#pragma unroll
    for (int j = 0; j < 4; j++) {
        int idx = base + j;
        if (idx < n) offs[idx] = prefix;
        prefix += v[j];
    }
}

// ============ CSR scatter ============
__global__ void scatter_kernel(const int* __restrict__ ei, int Edir,
                               const float* __restrict__ maskf,
                               const int* __restrict__ cnt, const int* __restrict__ offs,
                               int* __restrict__ cursor,
                               int* __restrict__ cnbr, float* __restrict__ cwA, int Eund)
{
    int e = blockIdx.x * 256 + threadIdx.x;
    if (e >= Eund) return;
    if (maskf[e] == 0.f) return;
    int row = ei[e], col = ei[Edir + e];
    row = min(max(row, 0), N_NUM - 1);
    col = min(max(col, 0), N_NUM - 1);
    float w = 1.0f / sqrtf((float)cnt[row] * (float)cnt[col]);
    int p1 = offs[row] + atomicAdd(&cursor[row], 1);
    cnbr[p1] = col; cwA[p1] = w;
    int p2 = offs[col] + atomicAdd(&cursor[col], 1);
    cnbr[p2] = row; cwA[p2] = w;
}

// ============ propagation ============
// Only nodes with surviving edges ever have their x1/x2 rows READ (gathers go
// through cnbr, whose entries all have cnt>0), so MODE 0/1 skip writes for
// isolated nodes and MODE 2 reads intermediates only when cnt>0.
// MODE 2 also fuses the user/item embed copy into d_out's tail.
template<int MODE>
__global__ __launch_bounds__(256)
void prop(const int* __restrict__ offs, const int* __restrict__ cnt,
          const int* __restrict__ cnbr, const float* __restrict__ cwA,
          const float* __restrict__ xin,
          const float* __restrict__ ue, const float* __restrict__ ie,
          const float* __restrict__ x1b, float* __restrict__ xout,
          float* __restrict__ tail)
{
    int wid = (blockIdx.x << 2) + (threadIdx.x >> 6);
    if (wid >= N_NUM) return;
    int lane = threadIdx.x & 63;
    int num = cnt[wid];
    if (MODE != 2 && num == 0) return;   // nobody will read this row
    int start = (num > 0) ? offs[wid] : 0;
    float ax = 0.f, ay = 0.f;

    auto srcp = [&](int c) -> const float* {
        if (MODE == 0)
            return (c < U_NUM) ? (ue + (size_t)c * D_EMB) : (ie + (size_t)(c - U_NUM) * D_EMB);
        else
            return xin + (size_t)c * D_EMB;
    };

    int j = 0;
    for (; j + 4 <= num; j += 4) {
        int c0i = cnbr[start + j],     c1i = cnbr[start + j + 1];
        int c2i = cnbr[start + j + 2], c3i = cnbr[start + j + 3];
        float w0 = cwA[start + j],     w1 = cwA[start + j + 1];
        float w2 = cwA[start + j + 2], w3 = cwA[start + j + 3];
        float2 v0 = *(const float2*)(srcp(c0i) + lane * 2);
        float2 v1 = *(const float2*)(srcp(c1i) + lane * 2);
        float2 v2 = *(const float2*)(srcp(c2i) + lane * 2);
        float2 v3 = *(const float2*)(srcp(c3i) + lane * 2);
        ax += w0 * v0.x; ay += w0 * v0.y;
        ax += w1 * v1.x; ay += w1 * v1.y;
        ax += w2 * v2.x; ay += w2 * v2.y;
        ax += w3 * v3.x; ay += w3 * v3.y;
    }
    for (; j < num; ++j) {
        int c = cnbr[start + j]; float w = cwA[start + j];
        float2 v = *(const float2*)(srcp(c) + lane * 2);
        ax += w * v.x; ay += w * v.y;
    }

    size_t o = (size_t)wid * D_EMB + lane * 2;
    if (MODE == 2) {
        const float* x0p = (wid < U_NUM) ? (ue + (size_t)wid * D_EMB)
                                         : (ie + (size_t)(wid - U_NUM) * D_EMB);
        float2 x0v = *(const float2*)(x0p + lane * 2);
        *(float2*)(tail + o) = x0v;                     // embed copy (output tail)
        float ox, oy;
        if (num == 0) {
            ox = x0v.x * 0.25f; oy = x0v.y * 0.25f;
        } else {
            float2 x1v = *(const float2*)(x1b + o);
            float2 x2v = *(const float2*)(xin + o);
            ox = ((x0v.x + x1v.x) + x2v.x + ax) * 0.25f;
            oy = ((x0v.y + x1v.y) + x2v.y + ay) * 0.25f;
        }
        *(float2*)(xout + o) = make_float2(ox, oy);
    } else {
        *(float2*)(xout + o) = make_float2(ax, ay);
    }
}

// ============ launcher ============
extern "C" void kernel_launch(void* const* d_in, const int* in_sizes, int n_in,
                              void* d_out, int out_size, void* d_ws, size_t ws_size,
                              hipStream_t stream)
{
    const float* user_feat  = (const float*)d_in[0];
    const float* food_feat  = (const float*)d_in[1];
    const int*   ei         = (const int*)d_in[2];
    const float* W_user     = (const float*)d_in[3];
    const float* b_user     = (const float*)d_in[4];
    const float* W_food     = (const float*)d_in[5];
    const float* b_food     = (const float*)d_in[6];
    const float* Wq         = (const float*)d_in[7];
    const float* Wk         = (const float*)d_in[8];
    const float* cwts       = (const float*)d_in[9];
    const float* user_embed = (const float*)d_in[10];
    const float* item_embed = (const float*)d_in[11];

    const int Edir = in_sizes[2] / 2;   // 1.2M directed edges
    const int Eund = Edir / 2;          // 600K undirected ([u,f] || [f,u])

    char* ws = (char*)d_ws;
    size_t off = 0;
    auto alloc = [&](size_t nb) { size_t o = off; off += (nb + 255) & ~(size_t)255; return o; };

    float* Q     = (float*)(ws + alloc((size_t)U_NUM * D_EMB * 4));  // Q|Kf contiguous -> xA
    float* Kf    = (float*)(ws + alloc((size_t)F_NUM * D_EMB * 4));
    float* xB    = (float*)(ws + alloc((size_t)N_NUM * D_EMB * 4));
    float* maskf = (float*)(ws + alloc((size_t)Eund * 4));
    int*   cnt   = (int*)  (ws + alloc((size_t)N_NUM * 4));
    int*   offs  = (int*)  (ws + alloc((size_t)N_NUM * 4));
    int*   cursor= (int*)  (ws + alloc((size_t)N_NUM * 4));
    int*   cnbr  = (int*)  (ws + alloc((size_t)Edir * 4));
    float* cwA   = (float*)(ws + alloc((size_t)Edir * 4));
    int*   part  = (int*)  (ws + alloc((size_t)256 * 4));
    unsigned short* Wsp = (unsigned short*)(ws + alloc((size_t)196608 * 2));
    (void)ws_size; (void)n_in; (void)out_size;

    float* xA = Q;   // N x 128, reuses Q|Kf after the edge stage

    // 1) pre-split weights + zero counters (one kernel)
    presplit_zero<<<384, 256, 0, stream>>>(W_user, W_food, Wq, Wk, Wsp, cnt, cursor);

    // 2) fused projections via split-fp16 MFMA
    const int nbU = (U_NUM + 127) / 128;   // 391
    const int nbF = (F_NUM + 127) / 128;   // 157
    fused_proj_mfma<<<nbU + nbF, 256, 0, stream>>>(user_feat, food_feat, Wsp,
                                                   b_user, b_food, Q, Kf, nbU);

    // 3) per-edge mask + degree counts
    edge_kernel<<<(Eund * 8 + 255) / 256, 256, 0, stream>>>(ei, Edir, Q, Kf, cwts,
                                                            maskf, cnt, Eund);

    // 4) exclusive scan of cnt -> offs
    int nb = (N_NUM + 1023) / 1024;
    scan_part <<<nb, 256, 0, stream>>>(cnt, part, N_NUM);
    scan_small<<<1, 256, 0, stream>>>(part, nb);
    scan_final<<<nb, 256, 0, stream>>>(cnt, part, offs, N_NUM);

    // 5) CSR scatter
    scatter_kernel<<<(Eund + 255) / 256, 256, 0, stream>>>(ei, Edir, maskf, cnt, offs,
                                                           cursor, cnbr, cwA, Eund);

    // 6) three LightGCN layers (skip-write for isolated nodes); last layer fuses
    //    the (x0+x1+x2+x3)/4 epilogue AND the embeds tail copy.
    int pb = (N_NUM + 3) / 4;
    float* tail = (float*)d_out + (size_t)N_NUM * D_EMB;
    prop<0><<<pb, 256, 0, stream>>>(offs, cnt, cnbr, cwA, nullptr, user_embed, item_embed,
                                    nullptr, xB, nullptr);
    prop<1><<<pb, 256, 0, stream>>>(offs, cnt, cnbr, cwA, xB, user_embed, item_embed,
                                    nullptr, xA, nullptr);
    prop<2><<<pb, 256, 0, stream>>>(offs, cnt, cnbr, cwA, xA, user_embed, item_embed,
                                    xB, (float*)d_out, tail);
}

// Round 6
// 184.637 us; speedup vs baseline: 2.9894x; 1.1285x over previous
//
#include <hip/hip_runtime.h>
#include <cstdint>

#define U_NUM 50000
#define F_NUM 20000
#define N_NUM 70000
#define D_EMB 128
#define THRESH 0.3f

typedef _Float16 half8 __attribute__((ext_vector_type(8)));
typedef float f32x4 __attribute__((ext_vector_type(4)));

// ============ pre-split weights (2 fp16 planes, transposed [n][k]) + zero counters ============
// dst layout (ushort elems):
//  W1u: [0)        2 planes x [128n][256k]  (plane stride 32768)
//  W1f: [65536)    same
//  Wq : [131072)   2 planes x [128n][128k]  (plane stride 16384)
//  Wk : [163840)   same                      total 196608
__global__ void presplit_zero(const float* __restrict__ Wu, const float* __restrict__ Wf,
                              const float* __restrict__ Wq, const float* __restrict__ Wk,
                              unsigned short* __restrict__ dst,
                              int* __restrict__ cnt, int* __restrict__ cursor)
{
    int i = blockIdx.x * 256 + threadIdx.x;
    if (i < N_NUM) { cnt[i] = 0; cursor[i] = 0; }
    if (i >= 98304) return;
    float a; size_t d; int pstride;
    if (i < 32768) {
        int n = i >> 8, k = i & 255;
        a = Wu[k * 128 + n]; d = (size_t)n * 256 + k; pstride = 32768;
    } else if (i < 65536) {
        int j = i - 32768; int n = j >> 8, k = j & 255;
        a = Wf[k * 128 + n]; d = 65536 + (size_t)n * 256 + k; pstride = 32768;
    } else if (i < 81920) {
        int j = i - 65536; int n = j >> 7, k = j & 127;
        a = Wq[k * 128 + n]; d = 131072 + (size_t)n * 128 + k; pstride = 16384;
    } else {
        int j = i - 81920; int n = j >> 7, k = j & 127;
        a = Wk[k * 128 + n]; d = 163840 + (size_t)n * 128 + k; pstride = 16384;
    }
    _Float16 c1 = (_Float16)a;            // RNE
    float r = a - (float)c1;
    _Float16 c2 = (_Float16)r;            // RNE
    dst[d]           = __builtin_bit_cast(unsigned short, c1);
    dst[d + pstride] = __builtin_bit_cast(unsigned short, c2);
}

// ============ split 8 f32 -> hi/lo fp16 fragments (RNE scalar casts) ============
__device__ __forceinline__ void split2(const float4 x0, const float4 x1,
                                       half8& h, half8& lo)
{
    float v[8] = {x0.x, x0.y, x0.z, x0.w, x1.x, x1.y, x1.z, x1.w};
#pragma unroll
    for (int i = 0; i < 8; i++) {
        _Float16 c1 = (_Float16)v[i];
        h[i] = c1;
        lo[i] = (_Float16)(v[i] - (float)c1);
    }
}

// ============ GEMM via split-fp16 MFMA (3-product), B LDS-staged, dbuf ============
// KDIM=256: E[comb] = relu(feat @ W1 + b1);  KDIM=128: QK[comb] = E @ W2.
// Block: 256 thr = 4 waves x (32 rows x 64 cols); grid = 2*(nbU+nbF) (col-split x2).
// LDS: 2 bufs x 2 planes x [64 n][40 halfs] (80-B pitch -> balanced b128 reads).
template<int KDIM>
__global__ __launch_bounds__(256, 4)
void gemm_split(const float* __restrict__ uf, const float* __restrict__ ff,
                const float* __restrict__ Ein,
                const unsigned short* __restrict__ Wsp,
                const float* __restrict__ bu, const float* __restrict__ bfo,
                float* __restrict__ outb, int nbU2)
{
    constexpr int NK = KDIM / 32;
    __shared__ unsigned short Bs[2][2][64][40];   // 20480 B

    const int bid = blockIdx.x;
    const bool isU = bid < nbU2;
    const int lb  = isU ? bid : bid - nbU2;
    const int rowTile = lb >> 1;
    const int colHalf = lb & 1;
    const int n0 = colHalf * 64;
    const int Mloc = isU ? U_NUM : F_NUM;
    const int combBase = isU ? 0 : U_NUM;
    const unsigned short* W = Wsp + (KDIM == 256 ? (isU ? 0 : 65536)
                                                 : (isU ? 131072 : 163840));
    const int Wp = KDIM * 128;   // plane stride (ushorts)

    const int tid = threadIdx.x;
    const int w  = tid >> 6;
    const int l  = tid & 63;
    const int lm = l & 15;
    const int lq = l >> 4;
    const int wr = w * 32;       // wave's row offset within block

    // staging role: thread copies 32 B of one (plane, n)-row
    const int sp = tid >> 7;
    const int sn = (tid >> 1) & 63;
    const int sh = tid & 1;
    const unsigned short* wsrc = W + (size_t)sp * Wp + (size_t)(n0 + sn) * KDIM + sh * 16;

    auto stage = [&](int buf, int kc) {
        const unsigned short* s = wsrc + kc * 32;
        uint4 v0 = *(const uint4*)(s);
        uint4 v1 = *(const uint4*)(s + 8);
        *(uint4*)&Bs[buf][sp][sn][sh * 16]     = v0;
        *(uint4*)&Bs[buf][sp][sn][sh * 16 + 8] = v1;
    };

    f32x4 acc[2][4];
#pragma unroll
    for (int i = 0; i < 2; i++)
#pragma unroll
        for (int j = 0; j < 4; j++) acc[i][j] = (f32x4)0.f;

    stage(0, 0);
    __syncthreads();
    int buf = 0;
    for (int kc = 0; kc < NK; ++kc) {
        if (kc + 1 < NK) stage(buf ^ 1, kc + 1);

        half8 a1[2], a2[2];
#pragma unroll
        for (int rb = 0; rb < 2; ++rb) {
            int lr = wr + rb * 16 + lm;
            const float* ap;
            if constexpr (KDIM == 256) {
                int r = min(rowTile * 128 + lr, Mloc - 1);
                ap = (isU ? uf : ff) + (size_t)r * 256;
            } else {
                int r = min(rowTile * 128 + lr, Mloc - 1) + combBase;
                ap = Ein + (size_t)r * 128;
            }
            const float4* p4 = (const float4*)(ap + kc * 32 + lq * 8);
            split2(p4[0], p4[1], a1[rb], a2[rb]);
        }
#pragma unroll
        for (int cb = 0; cb < 4; ++cb) {
            const unsigned short* bp = &Bs[buf][0][cb * 16 + lm][lq * 8];
            half8 bh = *(const half8*)bp;
            half8 bl = *(const half8*)(bp + 64 * 40);
#pragma unroll
            for (int rb = 0; rb < 2; ++rb) {
                acc[rb][cb] = __builtin_amdgcn_mfma_f32_16x16x32_f16(a2[rb], bh, acc[rb][cb], 0, 0, 0);
                acc[rb][cb] = __builtin_amdgcn_mfma_f32_16x16x32_f16(a1[rb], bl, acc[rb][cb], 0, 0, 0);
                acc[rb][cb] = __builtin_amdgcn_mfma_f32_16x16x32_f16(a1[rb], bh, acc[rb][cb], 0, 0, 0);
            }
        }
        __syncthreads();
        buf ^= 1;
    }

    // epilogue
#pragma unroll
    for (int cb = 0; cb < 4; ++cb) {
        const int col = n0 + cb * 16 + lm;
        float bb = 0.f;
        if constexpr (KDIM == 256) bb = (isU ? bu : bfo)[col];
#pragma unroll
        for (int rb = 0; rb < 2; ++rb)
#pragma unroll
            for (int rg = 0; rg < 4; ++rg) {
                int lr = wr + rb * 16 + lq * 4 + rg;
                if (rowTile * 128 + lr < Mloc) {
                    size_t r = (size_t)(combBase + rowTile * 128 + lr);
                    float v = acc[rb][cb][rg];
                    if constexpr (KDIM == 256) v = fmaxf(v + bb, 0.f);
                    outb[r * 128 + col] = v;
                }
            }
    }
}

// ============ per-(undirected)-edge multi-head cosine mask ============
__global__ __launch_bounds__(256)
void edge_kernel(const int* __restrict__ ei, int Edir,
                 const float* __restrict__ Q, const float* __restrict__ Kf,
                 const float* __restrict__ cwts,
                 float* __restrict__ maskf, int* __restrict__ cnt, int Eund)
{
    int gid = blockIdx.x * 256 + threadIdx.x;
    int e = gid >> 3;
    if (e >= Eund) return;
    int sub = gid & 7;
    int row = ei[e];
    int col = ei[Edir + e];
    row = min(max(row, 0), N_NUM - 1);
    col = min(max(col, 0), N_NUM - 1);
    int u  = (row < U_NUM) ? row : col;
    int fg = (row < U_NUM) ? col : row;
    u = min(max(u, 0), U_NUM - 1);
    int f = min(max(fg - U_NUM, 0), F_NUM - 1);

    const float4* qp = (const float4*)(Q  + (size_t)u * D_EMB + sub * 16);
    const float4* kp = (const float4*)(Kf + (size_t)f * D_EMB + sub * 16);
    float dot = 0.f, qq = 0.f, kk = 0.f;
#pragma unroll
    for (int i = 0; i < 4; i++) {
        float4 a = qp[i]; float4 b = kp[i];
        dot += a.x * b.x + a.y * b.y + a.z * b.z + a.w * b.w;
        qq  += a.x * a.x + a.y * a.y + a.z * a.z + a.w * a.w;
        kk  += b.x * b.x + b.y * b.y + b.z * b.z + b.w * b.w;
    }
    dot += __shfl_xor(dot, 1);           // 16+16 -> 32-elem head reductions
    qq  += __shfl_xor(qq, 1);
    kk  += __shfl_xor(kk, 1);
    float denom = sqrtf(qq) * sqrtf(kk) + 1e-8f;
    float sim = dot / denom;
    float s = sim + __shfl_xor(sim, 2);  // pairs of heads
    s += __shfl_xor(s, 4);               // all 4 heads
    float mean = s * 0.25f;
    float mf = (mean > THRESH) ? 1.f : 0.f;

    float cw0 = cwts[0], cw1 = cwts[1];
    float mx = fmaxf(cw0, cw1);
    float e0 = expf(cw0 - mx), e1 = expf(cw1 - mx);
    float inv = 1.f / (e0 + e1);
    float fused = e0 * inv + (e1 * inv) * mf;
    float em = (fused > 0.5f) ? 1.f : 0.f;

    if (sub == 0) {
        maskf[e] = em;
        if (em != 0.f) {
            atomicAdd(&cnt[row], 1);
            atomicAdd(&cnt[col], 1);
        }
    }
}

// ============ exclusive scan over cnt[N] (3 kernels) ============
__global__ void scan_part(const int* __restrict__ cnt, int* __restrict__ part, int n)
{
    __shared__ int sd[256];
    int b = blockIdx.x, t = threadIdx.x;
    int base = b * 1024;
    int s = 0;
#pragma unroll
    for (int j = 0; j < 4; j++) {
        int idx = base + t + j * 256;
        if (idx < n) s += cnt[idx];
    }
    sd[t] = s; __syncthreads();
    for (int d = 128; d > 0; d >>= 1) {
        if (t < d) sd[t] += sd[t + d];
        __syncthreads();
    }
    if (t == 0) part[b] = sd[0];
}

__global__ void scan_small(int* part, int nb)
{
    __shared__ int sd[256];
    int t = threadIdx.x;
    sd[t] = (t < nb) ? part[t] : 0;
    __syncthreads();
    for (int d = 1; d < 256; d <<= 1) {
        int x = (t >= d) ? sd[t - d] : 0;
        __syncthreads();
        sd[t] += x;
        __syncthreads();
    }
    if (t < nb) part[t] = (t > 0) ? sd[t - 1] : 0;
}

__global__ void scan_final(const int* __restrict__ cnt, const int* __restrict__ part,
                           int* __restrict__ offs, int n)
{
    __shared__ int sd[256];
    int b = blockIdx.x, t = threadIdx.x;
    int base = b * 1024 + t * 4;
    int v[4]; int s = 0;
#pragma unroll
    for (int j = 0; j < 4; j++) {
        int idx = base + j;
        v[j] = (idx < n) ? cnt[idx] : 0;
        s += v[j];
    }
    sd[t] = s; __syncthreads();
    for (int d = 1; d < 256; d <<= 1) {
        int x = (t >= d) ? sd[t - d] : 0;
        __syncthreads();
        sd[t] += x;
        __syncthreads();
    }
    int prefix = part[b] + ((t > 0) ? sd[t - 1] : 0);
#pragma unroll
    for (int j = 0; j < 4; j++) {
        int idx = base + j;
        if (idx < n) offs[idx] = prefix;
        prefix += v[j];
    }
}

// ============ CSR scatter ============
__global__ void scatter_kernel(const int* __restrict__ ei, int Edir,
                               const float* __restrict__ maskf,
                               const int* __restrict__ cnt, const int* __restrict__ offs,
                               int* __restrict__ cursor,
                               int* __restrict__ cnbr, float* __restrict__ cwA, int Eund)
{
    int e = blockIdx.x * 256 + threadIdx.x;
    if (e >= Eund) return;
    if (maskf[e] == 0.f) return;
    int row = ei[e], col = ei[Edir + e];
    row = min(max(row, 0), N_NUM - 1);
    col = min(max(col, 0), N_NUM - 1);
    float w = 1.0f / sqrtf((float)cnt[row] * (float)cnt[col]);
    int p1 = offs[row] + atomicAdd(&cursor[row], 1);
    cnbr[p1] = col; cwA[p1] = w;
    int p2 = offs[col] + atomicAdd(&cursor[col], 1);
    cnbr[p2] = row; cwA[p2] = w;
}

// ============ propagation ============
// Only nodes with surviving edges ever have their x1/x2 rows READ, so MODE 0/1
// skip writes for isolated nodes; MODE 2 fuses the epilogue + embed tail copy.
template<int MODE>
__global__ __launch_bounds__(256)
void prop(const int* __restrict__ offs, const int* __restrict__ cnt,
          const int* __restrict__ cnbr, const float* __restrict__ cwA,
          const float* __restrict__ xin,
          const float* __restrict__ ue, const float* __restrict__ ie,
          const float* __restrict__ x1b, float* __restrict__ xout,
          float* __restrict__ tail)
{
    int wid = (blockIdx.x << 2) + (threadIdx.x >> 6);
    if (wid >= N_NUM) return;
    int lane = threadIdx.x & 63;
    int num = cnt[wid];
    if (MODE != 2 && num == 0) return;
    int start = (num > 0) ? offs[wid] : 0;
    float ax = 0.f, ay = 0.f;

    auto srcp = [&](int c) -> const float* {
        if (MODE == 0)
            return (c < U_NUM) ? (ue + (size_t)c * D_EMB) : (ie + (size_t)(c - U_NUM) * D_EMB);
        else
            return xin + (size_t)c * D_EMB;
    };

    int j = 0;
    for (; j + 4 <= num; j += 4) {
        int c0i = cnbr[start + j],     c1i = cnbr[start + j + 1];
        int c2i = cnbr[start + j + 2], c3i = cnbr[start + j + 3];
        float w0 = cwA[start + j],     w1 = cwA[start + j + 1];
        float w2 = cwA[start + j + 2], w3 = cwA[start + j + 3];
        float2 v0 = *(const float2*)(srcp(c0i) + lane * 2);
        float2 v1 = *(const float2*)(srcp(c1i) + lane * 2);
        float2 v2 = *(const float2*)(srcp(c2i) + lane * 2);
        float2 v3 = *(const float2*)(srcp(c3i) + lane * 2);
        ax += w0 * v0.x; ay += w0 * v0.y;
        ax += w1 * v1.x; ay += w1 * v1.y;
        ax += w2 * v2.x; ay += w2 * v2.y;
        ax += w3 * v3.x; ay += w3 * v3.y;
    }
    for (; j < num; ++j) {
        int c = cnbr[start + j]; float w = cwA[start + j];
        float2 v = *(const float2*)(srcp(c) + lane * 2);
        ax += w * v.x; ay += w * v.y;
    }

    size_t o = (size_t)wid * D_EMB + lane * 2;
    if (MODE == 2) {
        const float* x0p = (wid < U_NUM) ? (ue + (size_t)wid * D_EMB)
                                         : (ie + (size_t)(wid - U_NUM) * D_EMB);
        float2 x0v = *(const float2*)(x0p + lane * 2);
        *(float2*)(tail + o) = x0v;                     // embed copy (output tail)
        float ox, oy;
        if (num == 0) {
            ox = x0v.x * 0.25f; oy = x0v.y * 0.25f;
        } else {
            float2 x1v = *(const float2*)(x1b + o);
            float2 x2v = *(const float2*)(xin + o);
            ox = ((x0v.x + x1v.x) + x2v.x + ax) * 0.25f;
            oy = ((x0v.y + x1v.y) + x2v.y + ay) * 0.25f;
        }
        *(float2*)(xout + o) = make_float2(ox, oy);
    } else {
        *(float2*)(xout + o) = make_float2(ax, ay);
    }
}

// ============ launcher ============
extern "C" void kernel_launch(void* const* d_in, const int* in_sizes, int n_in,
                              void* d_out, int out_size, void* d_ws, size_t ws_size,
                              hipStream_t stream)
{
    const float* user_feat  = (const float*)d_in[0];
    const float* food_feat  = (const float*)d_in[1];
    const int*   ei         = (const int*)d_in[2];
    const float* W_user     = (const float*)d_in[3];
    const float* b_user     = (const float*)d_in[4];
    const float* W_food     = (const float*)d_in[5];
    const float* b_food     = (const float*)d_in[6];
    const float* Wq         = (const float*)d_in[7];
    const float* Wk         = (const float*)d_in[8];
    const float* cwts       = (const float*)d_in[9];
    const float* user_embed = (const float*)d_in[10];
    const float* item_embed = (const float*)d_in[11];

    const int Edir = in_sizes[2] / 2;   // 1.2M directed edges
    const int Eund = Edir / 2;          // 600K undirected ([u,f] || [f,u])

    char* ws = (char*)d_ws;
    size_t off = 0;
    auto alloc = [&](size_t nb) { size_t o = off; off += (nb + 255) & ~(size_t)255; return o; };

    float* Q     = (float*)(ws + alloc((size_t)U_NUM * D_EMB * 4));  // Q|Kf contiguous -> xA
    float* Kf    = (float*)(ws + alloc((size_t)F_NUM * D_EMB * 4));
    float* xB    = (float*)(ws + alloc((size_t)N_NUM * D_EMB * 4));  // E, later prop scratch
    float* maskf = (float*)(ws + alloc((size_t)Eund * 4));
    int*   cnt   = (int*)  (ws + alloc((size_t)N_NUM * 4));
    int*   offs  = (int*)  (ws + alloc((size_t)N_NUM * 4));
    int*   cursor= (int*)  (ws + alloc((size_t)N_NUM * 4));
    int*   cnbr  = (int*)  (ws + alloc((size_t)Edir * 4));
    float* cwA   = (float*)(ws + alloc((size_t)Edir * 4));
    int*   part  = (int*)  (ws + alloc((size_t)256 * 4));
    unsigned short* Wsp = (unsigned short*)(ws + alloc((size_t)196608 * 2));
    (void)ws_size; (void)n_in; (void)out_size;

    float* xA = Q;    // N x 128, reuses Q|Kf after the edge stage
    float* E  = xB;   // N x 128 intermediate (dead before prop<0> writes xB)

    // 1) pre-split weights + zero counters
    presplit_zero<<<384, 256, 0, stream>>>(W_user, W_food, Wq, Wk, Wsp, cnt, cursor);

    // 2) two GEMMs: E = relu(feat@W1+b1); QK = E@W2   (col-split x2 grids)
    const int nbU2 = 2 * ((U_NUM + 127) / 128);   // 782
    const int nbF2 = 2 * ((F_NUM + 127) / 128);   // 314
    gemm_split<256><<<nbU2 + nbF2, 256, 0, stream>>>(user_feat, food_feat, nullptr, Wsp,
                                                     b_user, b_food, E, nbU2);
    gemm_split<128><<<nbU2 + nbF2, 256, 0, stream>>>(nullptr, nullptr, E, Wsp,
                                                     nullptr, nullptr, Q, nbU2);

    // 3) per-edge mask + degree counts
    edge_kernel<<<(Eund * 8 + 255) / 256, 256, 0, stream>>>(ei, Edir, Q, Kf, cwts,
                                                            maskf, cnt, Eund);

    // 4) exclusive scan of cnt -> offs
    int nb = (N_NUM + 1023) / 1024;
    scan_part <<<nb, 256, 0, stream>>>(cnt, part, N_NUM);
    scan_small<<<1, 256, 0, stream>>>(part, nb);
    scan_final<<<nb, 256, 0, stream>>>(cnt, part, offs, N_NUM);

    // 5) CSR scatter
    scatter_kernel<<<(Eund + 255) / 256, 256, 0, stream>>>(ei, Edir, maskf, cnt, offs,
                                                           cursor, cnbr, cwA, Eund);

    // 6) three LightGCN layers (skip-write for isolated nodes); last layer fuses
    //    the (x0+x1+x2+x3)/4 epilogue AND the embeds tail copy.
    int pb = (N_NUM + 3) / 4;
    float* tail = (float*)d_out + (size_t)N_NUM * D_EMB;
    prop<0><<<pb, 256, 0, stream>>>(offs, cnt, cnbr, cwA, nullptr, user_embed, item_embed,
                                    nullptr, xB, nullptr);
    prop<1><<<pb, 256, 0, stream>>>(offs, cnt, cnbr, cwA, xB, user_embed, item_embed,
                                    nullptr, xA, nullptr);
    prop<2><<<pb, 256, 0, stream>>>(offs, cnt, cnbr, cwA, xA, user_embed, item_embed,
                                    xB, (float*)d_out, tail);
}

// Round 7
// 151.371 us; speedup vs baseline: 3.6464x; 1.2198x over previous
//
#include <hip/hip_runtime.h>
#include <cstdint>

#define U_NUM 50000
#define F_NUM 20000
#define N_NUM 70000
#define D_EMB 128
#define THRESH 0.3f

typedef _Float16 half8 __attribute__((ext_vector_type(8)));
typedef float f32x4 __attribute__((ext_vector_type(4)));
typedef unsigned short u16x8 __attribute__((ext_vector_type(8)));

// ============ pre-split weights (2 fp16 planes, transposed [n][k]) + zero counters ============
__global__ void presplit_zero(const float* __restrict__ Wu, const float* __restrict__ Wf,
                              const float* __restrict__ Wq, const float* __restrict__ Wk,
                              unsigned short* __restrict__ dst,
                              int* __restrict__ cnt, int* __restrict__ cursor)
{
    int i = blockIdx.x * 256 + threadIdx.x;
    if (i < N_NUM) { cnt[i] = 0; cursor[i] = 0; }
    if (i >= 98304) return;
    float a; size_t d; int pstride;
    if (i < 32768) {
        int n = i >> 8, k = i & 255;
        a = Wu[k * 128 + n]; d = (size_t)n * 256 + k; pstride = 32768;
    } else if (i < 65536) {
        int j = i - 32768; int n = j >> 8, k = j & 255;
        a = Wf[k * 128 + n]; d = 65536 + (size_t)n * 256 + k; pstride = 32768;
    } else if (i < 81920) {
        int j = i - 65536; int n = j >> 7, k = j & 127;
        a = Wq[k * 128 + n]; d = 131072 + (size_t)n * 128 + k; pstride = 16384;
    } else {
        int j = i - 81920; int n = j >> 7, k = j & 127;
        a = Wk[k * 128 + n]; d = 163840 + (size_t)n * 128 + k; pstride = 16384;
    }
    _Float16 c1 = (_Float16)a;            // RNE
    float r = a - (float)c1;
    _Float16 c2 = (_Float16)r;            // RNE
    dst[d]           = __builtin_bit_cast(unsigned short, c1);
    dst[d + pstride] = __builtin_bit_cast(unsigned short, c2);
}

// ============ split 8 f32 -> hi/lo fp16 fragments (RNE scalar casts) ============
__device__ __forceinline__ void split2(const float4 x0, const float4 x1,
                                       half8& h, half8& lo)
{
    float v[8] = {x0.x, x0.y, x0.z, x0.w, x1.x, x1.y, x1.z, x1.w};
#pragma unroll
    for (int i = 0; i < 8; i++) {
        _Float16 c1 = (_Float16)v[i];
        h[i] = c1;
        lo[i] = (_Float16)(v[i] - (float)c1);
    }
}

// ============ GEMM via split-fp16 MFMA (3-product), B LDS-staged, dbuf ============
// KDIM=256: E[comb] = relu(feat @ W1 + b1);  KDIM=128: QK[comb] = E @ W2 (+fp16 copy).
template<int KDIM>
__global__ __launch_bounds__(256, 4)
void gemm_split(const float* __restrict__ uf, const float* __restrict__ ff,
                const float* __restrict__ Ein,
                const unsigned short* __restrict__ Wsp,
                const float* __restrict__ bu, const float* __restrict__ bfo,
                float* __restrict__ outb, unsigned short* __restrict__ outh, int nbU2)
{
    constexpr int NK = KDIM / 32;
    __shared__ unsigned short Bs[2][2][64][40];   // 20480 B

    const int bid = blockIdx.x;
    const bool isU = bid < nbU2;
    const int lb  = isU ? bid : bid - nbU2;
    const int rowTile = lb >> 1;
    const int colHalf = lb & 1;
    const int n0 = colHalf * 64;
    const int Mloc = isU ? U_NUM : F_NUM;
    const int combBase = isU ? 0 : U_NUM;
    const unsigned short* W = Wsp + (KDIM == 256 ? (isU ? 0 : 65536)
                                                 : (isU ? 131072 : 163840));
    const int Wp = KDIM * 128;   // plane stride (ushorts)

    const int tid = threadIdx.x;
    const int w  = tid >> 6;
    const int l  = tid & 63;
    const int lm = l & 15;
    const int lq = l >> 4;
    const int wr = w * 32;       // wave's row offset within block

    // staging role: thread copies 32 B of one (plane, n)-row
    const int sp = tid >> 7;
    const int sn = (tid >> 1) & 63;
    const int sh = tid & 1;
    const unsigned short* wsrc = W + (size_t)sp * Wp + (size_t)(n0 + sn) * KDIM + sh * 16;

    auto stage = [&](int buf, int kc) {
        const unsigned short* s = wsrc + kc * 32;
        uint4 v0 = *(const uint4*)(s);
        uint4 v1 = *(const uint4*)(s + 8);
        *(uint4*)&Bs[buf][sp][sn][sh * 16]     = v0;
        *(uint4*)&Bs[buf][sp][sn][sh * 16 + 8] = v1;
    };

    f32x4 acc[2][4];
#pragma unroll
    for (int i = 0; i < 2; i++)
#pragma unroll
        for (int j = 0; j < 4; j++) acc[i][j] = (f32x4)0.f;

    stage(0, 0);
    __syncthreads();
    int buf = 0;
    for (int kc = 0; kc < NK; ++kc) {
        if (kc + 1 < NK) stage(buf ^ 1, kc + 1);

        half8 a1[2], a2[2];
#pragma unroll
        for (int rb = 0; rb < 2; ++rb) {
            int lr = wr + rb * 16 + lm;
            const float* ap;
            if constexpr (KDIM == 256) {
                int r = min(rowTile * 128 + lr, Mloc - 1);
                ap = (isU ? uf : ff) + (size_t)r * 256;
            } else {
                int r = min(rowTile * 128 + lr, Mloc - 1) + combBase;
                ap = Ein + (size_t)r * 128;
            }
            const float4* p4 = (const float4*)(ap + kc * 32 + lq * 8);
            split2(p4[0], p4[1], a1[rb], a2[rb]);
        }
#pragma unroll
        for (int cb = 0; cb < 4; ++cb) {
            const unsigned short* bp = &Bs[buf][0][cb * 16 + lm][lq * 8];
            half8 bh = *(const half8*)bp;
            half8 bl = *(const half8*)(bp + 64 * 40);
#pragma unroll
            for (int rb = 0; rb < 2; ++rb) {
                acc[rb][cb] = __builtin_amdgcn_mfma_f32_16x16x32_f16(a2[rb], bh, acc[rb][cb], 0, 0, 0);
                acc[rb][cb] = __builtin_amdgcn_mfma_f32_16x16x32_f16(a1[rb], bl, acc[rb][cb], 0, 0, 0);
                acc[rb][cb] = __builtin_amdgcn_mfma_f32_16x16x32_f16(a1[rb], bh, acc[rb][cb], 0, 0, 0);
            }
        }
        __syncthreads();
        buf ^= 1;
    }

    // epilogue (f32 store; KDIM==128 also stores fp16 copy for the edge pass)
#pragma unroll
    for (int cb = 0; cb < 4; ++cb) {
        const int col = n0 + cb * 16 + lm;
        float bb = 0.f;
        if constexpr (KDIM == 256) bb = (isU ? bu : bfo)[col];
#pragma unroll
        for (int rb = 0; rb < 2; ++rb)
#pragma unroll
            for (int rg = 0; rg < 4; ++rg) {
                int lr = wr + rb * 16 + lq * 4 + rg;
                if (rowTile * 128 + lr < Mloc) {
                    size_t r = (size_t)(combBase + rowTile * 128 + lr);
                    float v = acc[rb][cb][rg];
                    if constexpr (KDIM == 256) v = fmaxf(v + bb, 0.f);
                    outb[r * 128 + col] = v;
                    if constexpr (KDIM == 128)
                        outh[r * 128 + col] = __builtin_bit_cast(unsigned short, (_Float16)v);
                }
            }
    }
}

// ============ per-edge multi-head cosine mask: fp16 gather + f32 borderline recheck ============
__global__ __launch_bounds__(256)
void edge_kernel(const int* __restrict__ ei, int Edir,
                 const unsigned short* __restrict__ QKh, const float* __restrict__ QKf,
                 const float* __restrict__ cwts,
                 float* __restrict__ maskf, int* __restrict__ cnt, int Eund)
{
    int gid = blockIdx.x * 256 + threadIdx.x;
    int e = gid >> 3;
    if (e >= Eund) return;
    int sub = gid & 7;
    int row = ei[e];
    int col = ei[Edir + e];
    row = min(max(row, 0), N_NUM - 1);
    col = min(max(col, 0), N_NUM - 1);
    int u  = (row < U_NUM) ? row : col;
    int fg = (row < U_NUM) ? col : row;
    u = min(max(u, 0), U_NUM - 1);
    int f = min(max(fg - U_NUM, 0), F_NUM - 1);
    const size_t qrow = (size_t)u * D_EMB;
    const size_t krow = (size_t)(U_NUM + f) * D_EMB;

    // fp16 fast path: 32 B per lane per row
    const unsigned short* qh = QKh + qrow + sub * 16;
    const unsigned short* kh = QKh + krow + sub * 16;
    u16x8 qa = *(const u16x8*)(qh);
    u16x8 qb = *(const u16x8*)(qh + 8);
    u16x8 ka = *(const u16x8*)(kh);
    u16x8 kb = *(const u16x8*)(kh + 8);
    float dot = 0.f, qq = 0.f, kk = 0.f;
#pragma unroll
    for (int i = 0; i < 8; i++) {
        float qv = (float)__builtin_bit_cast(_Float16, (unsigned short)qa[i]);
        float kv = (float)__builtin_bit_cast(_Float16, (unsigned short)ka[i]);
        dot += qv * kv; qq += qv * qv; kk += kv * kv;
    }
#pragma unroll
    for (int i = 0; i < 8; i++) {
        float qv = (float)__builtin_bit_cast(_Float16, (unsigned short)qb[i]);
        float kv = (float)__builtin_bit_cast(_Float16, (unsigned short)kb[i]);
        dot += qv * kv; qq += qv * qv; kk += kv * kv;
    }
    dot += __shfl_xor(dot, 1);           // 16+16 -> 32-elem head reductions
    qq  += __shfl_xor(qq, 1);
    kk  += __shfl_xor(kk, 1);
    float denom = sqrtf(qq) * sqrtf(kk) + 1e-8f;
    float sim = dot / denom;
    float s = sim + __shfl_xor(sim, 2);  // pairs of heads
    s += __shfl_xor(s, 4);               // all 4 heads
    float mean = s * 0.25f;              // uniform across the 8-lane group

    // borderline -> exact f32 recompute (identical arithmetic to the pure-f32 kernel)
    if (fabsf(mean - THRESH) < 0.03f) {
        const float4* qp = (const float4*)(QKf + qrow + sub * 16);
        const float4* kp = (const float4*)(QKf + krow + sub * 16);
        float dot2 = 0.f, qq2 = 0.f, kk2 = 0.f;
#pragma unroll
        for (int i = 0; i < 4; i++) {
            float4 a = qp[i]; float4 b = kp[i];
            dot2 += a.x * b.x + a.y * b.y + a.z * b.z + a.w * b.w;
            qq2  += a.x * a.x + a.y * a.y + a.z * a.z + a.w * a.w;
            kk2  += b.x * b.x + b.y * b.y + b.z * b.z + b.w * b.w;
        }
        dot2 += __shfl_xor(dot2, 1);
        qq2  += __shfl_xor(qq2, 1);
        kk2  += __shfl_xor(kk2, 1);
        float denom2 = sqrtf(qq2) * sqrtf(kk2) + 1e-8f;
        float sim2 = dot2 / denom2;
        float s2 = sim2 + __shfl_xor(sim2, 2);
        s2 += __shfl_xor(s2, 4);
        mean = s2 * 0.25f;
    }

    float mf = (mean > THRESH) ? 1.f : 0.f;
    float cw0 = cwts[0], cw1 = cwts[1];
    float mx = fmaxf(cw0, cw1);
    float e0 = expf(cw0 - mx), e1 = expf(cw1 - mx);
    float inv = 1.f / (e0 + e1);
    float fused = e0 * inv + (e1 * inv) * mf;
    float em = (fused > 0.5f) ? 1.f : 0.f;

    if (sub == 0) {
        maskf[e] = em;
        if (em != 0.f) {
            atomicAdd(&cnt[row], 1);
            atomicAdd(&cnt[col], 1);
        }
    }
}

// ============ exclusive scan over cnt[N] (3 kernels) ============
__global__ void scan_part(const int* __restrict__ cnt, int* __restrict__ part, int n)
{
    __shared__ int sd[256];
    int b = blockIdx.x, t = threadIdx.x;
    int base = b * 1024;
    int s = 0;
#pragma unroll
    for (int j = 0; j < 4; j++) {
        int idx = base + t + j * 256;
        if (idx < n) s += cnt[idx];
    }
    sd[t] = s; __syncthreads();
    for (int d = 128; d > 0; d >>= 1) {
        if (t < d) sd[t] += sd[t + d];
        __syncthreads();
    }
    if (t == 0) part[b] = sd[0];
}

__global__ void scan_small(int* part, int nb)
{
    __shared__ int sd[256];
    int t = threadIdx.x;
    sd[t] = (t < nb) ? part[t] : 0;
    __syncthreads();
    for (int d = 1; d < 256; d <<= 1) {
        int x = (t >= d) ? sd[t - d] : 0;
        __syncthreads();
        sd[t] += x;
        __syncthreads();
    }
    if (t < nb) part[t] = (t > 0) ? sd[t - 1] : 0;
}

__global__ void scan_final(const int* __restrict__ cnt, const int* __restrict__ part,
                           int* __restrict__ offs, int n)
{
    __shared__ int sd[256];
    int b = blockIdx.x, t = threadIdx.x;
    int base = b * 1024 + t * 4;
    int v[4]; int s = 0;
#pragma unroll
    for (int j = 0; j < 4; j++) {
        int idx = base + j;
        v[j] = (idx < n) ? cnt[idx] : 0;
        s += v[j];
    }
    sd[t] = s; __syncthreads();
    for (int d = 1; d < 256; d <<= 1) {
        int x = (t >= d) ? sd[t - d] : 0;
        __syncthreads();
        sd[t] += x;
        __syncthreads();
    }
    int prefix = part[b] + ((t > 0) ? sd[t - 1] : 0);
#pragma unroll
    for (int j = 0; j < 4; j++) {
        int idx = base + j;
        if (idx < n) offs[idx] = prefix;
        prefix += v[j];
    }
}

// ============ CSR scatter ============
__global__ void scatter_kernel(const int* __restrict__ ei, int Edir,
                               const float* __restrict__ maskf,
                               const int* __restrict__ cnt, const int* __restrict__ offs,
                               int* __restrict__ cursor,
                               int* __restrict__ cnbr, float* __restrict__ cwA, int Eund)
{
    int e = blockIdx.x * 256 + threadIdx.x;
    if (e >= Eund) return;
    if (maskf[e] == 0.f) return;
    int row = ei[e], col = ei[Edir + e];
    row = min(max(row, 0), N_NUM - 1);
    col = min(max(col, 0), N_NUM - 1);
    float w = 1.0f / sqrtf((float)cnt[row] * (float)cnt[col]);
    int p1 = offs[row] + atomicAdd(&cursor[row], 1);
    cnbr[p1] = col; cwA[p1] = w;
    int p2 = offs[col] + atomicAdd(&cursor[col], 1);
    cnbr[p2] = row; cwA[p2] = w;
}

// ============ propagation ============
template<int MODE>
__global__ __launch_bounds__(256)
void prop(const int* __restrict__ offs, const int* __restrict__ cnt,
          const int* __restrict__ cnbr, const float* __restrict__ cwA,
          const float* __restrict__ xin,
          const float* __restrict__ ue, const float* __restrict__ ie,
          const float* __restrict__ x1b, float* __restrict__ xout,
          float* __restrict__ tail)
{
    int wid = (blockIdx.x << 2) + (threadIdx.x >> 6);
    if (wid >= N_NUM) return;
    int lane = threadIdx.x & 63;
    int num = cnt[wid];
    if (MODE != 2 && num == 0) return;
    int start = (num > 0) ? offs[wid] : 0;
    float ax = 0.f, ay = 0.f;

    auto srcp = [&](int c) -> const float* {
        if (MODE == 0)
            return (c < U_NUM) ? (ue + (size_t)c * D_EMB) : (ie + (size_t)(c - U_NUM) * D_EMB);
        else
            return xin + (size_t)c * D_EMB;
    };

    int j = 0;
    for (; j + 4 <= num; j += 4) {
        int c0i = cnbr[start + j],     c1i = cnbr[start + j + 1];
        int c2i = cnbr[start + j + 2], c3i = cnbr[start + j + 3];
        float w0 = cwA[start + j],     w1 = cwA[start + j + 1];
        float w2 = cwA[start + j + 2], w3 = cwA[start + j + 3];
        float2 v0 = *(const float2*)(srcp(c0i) + lane * 2);
        float2 v1 = *(const float2*)(srcp(c1i) + lane * 2);
        float2 v2 = *(const float2*)(srcp(c2i) + lane * 2);
        float2 v3 = *(const float2*)(srcp(c3i) + lane * 2);
        ax += w0 * v0.x; ay += w0 * v0.y;
        ax += w1 * v1.x; ay += w1 * v1.y;
        ax += w2 * v2.x; ay += w2 * v2.y;
        ax += w3 * v3.x; ay += w3 * v3.y;
    }
    for (; j < num; ++j) {
        int c = cnbr[start + j]; float w = cwA[start + j];
        float2 v = *(const float2*)(srcp(c) + lane * 2);
        ax += w * v.x; ay += w * v.y;
    }

    size_t o = (size_t)wid * D_EMB + lane * 2;
    if (MODE == 2) {
        const float* x0p = (wid < U_NUM) ? (ue + (size_t)wid * D_EMB)
                                         : (ie + (size_t)(wid - U_NUM) * D_EMB);
        float2 x0v = *(const float2*)(x0p + lane * 2);
        *(float2*)(tail + o) = x0v;                     // embed copy (output tail)
        float ox, oy;
        if (num == 0) {
            ox = x0v.x * 0.25f; oy = x0v.y * 0.25f;
        } else {
            float2 x1v = *(const float2*)(x1b + o);
            float2 x2v = *(const float2*)(xin + o);
            ox = ((x0v.x + x1v.x) + x2v.x + ax) * 0.25f;
            oy = ((x0v.y + x1v.y) + x2v.y + ay) * 0.25f;
        }
        *(float2*)(xout + o) = make_float2(ox, oy);
    } else {
        *(float2*)(xout + o) = make_float2(ax, ay);
    }
}

// ============ launcher ============
extern "C" void kernel_launch(void* const* d_in, const int* in_sizes, int n_in,
                              void* d_out, int out_size, void* d_ws, size_t ws_size,
                              hipStream_t stream)
{
    const float* user_feat  = (const float*)d_in[0];
    const float* food_feat  = (const float*)d_in[1];
    const int*   ei         = (const int*)d_in[2];
    const float* W_user     = (const float*)d_in[3];
    const float* b_user     = (const float*)d_in[4];
    const float* W_food     = (const float*)d_in[5];
    const float* b_food     = (const float*)d_in[6];
    const float* Wq         = (const float*)d_in[7];
    const float* Wk         = (const float*)d_in[8];
    const float* cwts       = (const float*)d_in[9];
    const float* user_embed = (const float*)d_in[10];
    const float* item_embed = (const float*)d_in[11];

    const int Edir = in_sizes[2] / 2;   // 1.2M directed edges
    const int Eund = Edir / 2;          // 600K undirected ([u,f] || [f,u])

    char* ws = (char*)d_ws;
    size_t off = 0;
    auto alloc = [&](size_t nb) { size_t o = off; off += (nb + 255) & ~(size_t)255; return o; };

    float* Q     = (float*)(ws + alloc((size_t)N_NUM * D_EMB * 4));  // f32 Q|K (comb), -> xA
    float* xB    = (float*)(ws + alloc((size_t)N_NUM * D_EMB * 4));  // E, later prop scratch
    unsigned short* QKh = (unsigned short*)(ws + alloc((size_t)N_NUM * D_EMB * 2));
    float* maskf = (float*)(ws + alloc((size_t)Eund * 4));
    int*   cnt   = (int*)  (ws + alloc((size_t)N_NUM * 4));
    int*   offs  = (int*)  (ws + alloc((size_t)N_NUM * 4));
    int*   cursor= (int*)  (ws + alloc((size_t)N_NUM * 4));
    int*   cnbr  = (int*)  (ws + alloc((size_t)Edir * 4));
    float* cwA   = (float*)(ws + alloc((size_t)Edir * 4));
    int*   part  = (int*)  (ws + alloc((size_t)256 * 4));
    unsigned short* Wsp = (unsigned short*)(ws + alloc((size_t)196608 * 2));
    (void)ws_size; (void)n_in; (void)out_size;

    float* xA = Q;    // N x 128, reuses Q|K after the edge stage
    float* E  = xB;   // N x 128 intermediate (dead before prop<0> writes xB)

    // 1) pre-split weights + zero counters
    presplit_zero<<<384, 256, 0, stream>>>(W_user, W_food, Wq, Wk, Wsp, cnt, cursor);

    // 2) two GEMMs: E = relu(feat@W1+b1); QK = E@W2 (f32 + fp16 copies)
    const int nbU2 = 2 * ((U_NUM + 127) / 128);   // 782
    const int nbF2 = 2 * ((F_NUM + 127) / 128);   // 314
    gemm_split<256><<<nbU2 + nbF2, 256, 0, stream>>>(user_feat, food_feat, nullptr, Wsp,
                                                     b_user, b_food, E, nullptr, nbU2);
    gemm_split<128><<<nbU2 + nbF2, 256, 0, stream>>>(nullptr, nullptr, E, Wsp,
                                                     nullptr, nullptr, Q, QKh, nbU2);

    // 3) per-edge mask + degree counts (fp16 gather, f32 borderline recheck)
    edge_kernel<<<(Eund * 8 + 255) / 256, 256, 0, stream>>>(ei, Edir, QKh, Q, cwts,
                                                            maskf, cnt, Eund);

    // 4) exclusive scan of cnt -> offs
    int nb = (N_NUM + 1023) / 1024;
    scan_part <<<nb, 256, 0, stream>>>(cnt, part, N_NUM);
    scan_small<<<1, 256, 0, stream>>>(part, nb);
    scan_final<<<nb, 256, 0, stream>>>(cnt, part, offs, N_NUM);

    // 5) CSR scatter
    scatter_kernel<<<(Eund + 255) / 256, 256, 0, stream>>>(ei, Edir, maskf, cnt, offs,
                                                           cursor, cnbr, cwA, Eund);

    // 6) three LightGCN layers (skip-write for isolated nodes); last layer fuses
    //    the (x0+x1+x2+x3)/4 epilogue AND the embeds tail copy.
    int pb = (N_NUM + 3) / 4;
    float* tail = (float*)d_out + (size_t)N_NUM * D_EMB;
    prop<0><<<pb, 256, 0, stream>>>(offs, cnt, cnbr, cwA, nullptr, user_embed, item_embed,
                                    nullptr, xB, nullptr);
    prop<1><<<pb, 256, 0, stream>>>(offs, cnt, cnbr, cwA, xB, user_embed, item_embed,
                                    nullptr, xA, nullptr);
    prop<2><<<pb, 256, 0, stream>>>(offs, cnt, cnbr, cwA, xA, user_embed, item_embed,
                                    xB, (float*)d_out, tail);
}